// Round 8
// baseline (416.209 us; speedup 1.0000x reference)
//
#include <hip/hip_runtime.h>
#include <hip/hip_cooperative_groups.h>

namespace cg = cooperative_groups;

#define NN 50000
#define DD 128
#define NE 600000
#define NP 200000
#define NS 300000
#define NU 256
#define NBH 128
#define EPB 4688   // ceil(NE/NBH)
#define NW 12500   // NN/4 byte-packed words
#define NB64 782   // ceil(NN/64)

typedef __attribute__((ext_vector_type(8))) short short8;
typedef __attribute__((ext_vector_type(4))) float floatx4;

__device__ inline float bf2f(unsigned int u16) {
    unsigned int x = u16 << 16;
    float f; __builtin_memcpy(&f, &x, 4); return f;
}
__device__ inline unsigned short f2bf(float f) {
    unsigned int x; __builtin_memcpy(&x, &f, 4);
    unsigned int lsb = (x >> 16) & 1u;
    x += 0x7fffu + lsb;
    return (unsigned short)(x >> 16);
}

// ============ cooperative CSR build + weight cast, one kernel ============
// grid = 256 blocks x 256 threads, 50 KB LDS (1 block/CU -> co-resident).
// blocks 0..127: dst-half chunks (reused for bucket phase); 128..255: src-half.
__global__ __launch_bounds__(256) void k_csr_coop(
    const int* __restrict__ ei,
    const float* __restrict__ W1, const float* __restrict__ W2, const float* __restrict__ dW,
    unsigned short* __restrict__ BT1, unsigned short* __restrict__ BT2,
    unsigned short* __restrict__ BTd,
    unsigned int* __restrict__ P_hist, int* __restrict__ deg_in, float* __restrict__ r,
    int* __restrict__ row_ptr, int* __restrict__ basetab, int* __restrict__ col,
    int* __restrict__ blocksum, int* __restrict__ blockoff)
{
    __shared__ unsigned int hw[NW];
    cg::grid_group grid = cg::this_grid();
    int b = blockIdx.x, tid = threadIdx.x, lane = tid & 63;

    // ---- P1: per-block byte histogram ----
    for (int w = tid; w < NW; w += 256) hw[w] = 0;
    __syncthreads();
    int chunk = b & 127;
    const int* eptr = ei + (b < 128 ? NE : 0);   // b<128 counts dst, else src
    int e0 = chunk * EPB, e1 = min(e0 + EPB, NE);
    for (int e = e0 + tid; e < e1; e += 256) {
        int v = eptr[e];
        atomicAdd(&hw[v >> 2], 1u << ((v & 3) * 8));
    }
    __syncthreads();
    {
        unsigned int* Pb = P_hist + (size_t)b * NW;
        for (int w = tid; w < NW; w += 256) Pb[w] = hw[w];
    }
    grid.sync();

    // ---- P2: reduce partials -> deg_in + rsqrt; plus weight cast (65536 elems) ----
    int gid = b * 256 + tid;
    if (gid < 2 * NW) {
        int half = gid >= NW;                 // 0 = dst word, 1 = src word
        int wl = gid - half * NW;
        const unsigned int* Ph = P_hist + (size_t)(half ? 128 : 0) * NW + wl;
        int c0 = 0, c1 = 0, c2 = 0, c3 = 0;
        for (int b2 = 0; b2 < 128; ++b2) {
            unsigned int v = Ph[(size_t)b2 * NW];
            c0 += v & 0xff; c1 += (v >> 8) & 0xff; c2 += (v >> 16) & 0xff; c3 += v >> 24;
        }
        int nb4 = wl * 4;
        if (!half) { int4 d4 = {c0, c1, c2, c3}; *(int4*)(deg_in + nb4) = d4; }
        float4 rr = {rsqrtf((float)max(c0, 1)), rsqrtf((float)max(c1, 1)),
                     rsqrtf((float)max(c2, 1)), rsqrtf((float)max(c3, 1))};
        *(float4*)(r + (half ? 0 : NN) + nb4) = rr;   // dst->r_in(+NN), src->r_out(+0)
    }
    {
        int t = gid;
        if (t < 16384) { int rr = t >> 7, cc = t & 127; BT1[cc * 128 + rr] = f2bf(W1[t]); }
        else if (t < 32768) { int t2 = t - 16384; int rr = t2 >> 7, cc = t2 & 127; BT2[cc * 128 + rr] = f2bf(W2[t2]); }
        else { int t2 = t - 32768; int rr = t2 >> 8, cc = t2 & 255; BTd[cc * 128 + rr] = f2bf(dW[t2]); }
    }
    grid.sync();

    // ---- P3a: block-local sums over 49 int4 words (196 nodes/block) ----
    int w49 = b * 49 + tid;
    bool valid = (tid < 49) && (w49 < NW);
    int4 v4 = {0, 0, 0, 0};
    if (valid) v4 = *(const int4*)(deg_in + w49 * 4);
    if (tid < 64) {
        int s = v4.x + v4.y + v4.z + v4.w;
        int x = s;
#pragma unroll
        for (int off = 1; off < 64; off <<= 1) { int y = __shfl_up(x, off); if (lane >= off) x += y; }
        hw[tid] = (unsigned int)(x - s);          // exclusive prefix
        if (lane == 63) blocksum[b] = x;
    }
    grid.sync();

    // ---- P3b: block 0 scans the 256 blocksums ----
    if (b == 0 && tid < 64) {
        int s0 = blocksum[tid * 4], s1 = blocksum[tid * 4 + 1];
        int s2 = blocksum[tid * 4 + 2], s3 = blocksum[tid * 4 + 3];
        int tot = s0 + s1 + s2 + s3;
        int x = tot;
#pragma unroll
        for (int off = 1; off < 64; off <<= 1) { int y = __shfl_up(x, off); if (lane >= off) x += y; }
        int base0 = x - tot;
        blockoff[tid * 4]     = base0;
        blockoff[tid * 4 + 1] = base0 + s0;
        blockoff[tid * 4 + 2] = base0 + s0 + s1;
        blockoff[tid * 4 + 3] = base0 + s0 + s1 + s2;
    }
    grid.sync();

    // ---- P3c: row_ptr + per-node bases into LDS ----
    int bo = blockoff[b];
    if (valid) {
        int base = bo + (int)hw[tid];
        int4 o = {base, base + v4.x, base + v4.x + v4.y, base + v4.x + v4.y + v4.z};
        *(int4*)(row_ptr + w49 * 4) = o;
        hw[256 + tid * 4]     = (unsigned int)o.x;
        hw[256 + tid * 4 + 1] = (unsigned int)o.y;
        hw[256 + tid * 4 + 2] = (unsigned int)o.z;
        hw[256 + tid * 4 + 3] = (unsigned int)o.w;
    }
    if (b == 0 && tid == 0) row_ptr[NN] = NE;
    __syncthreads();

    // ---- P4: colscan for this block's 196 nodes ----
    int n = b * 196 + tid;
    if (tid < 196 && n < NN) {
        int run = (int)hw[256 + tid];
        int wl = n >> 2, sh = (n & 3) * 8;
        for (int b2 = 0; b2 < 128; ++b2) {
            basetab[(size_t)b2 * NN + n] = run;
            run += (P_hist[(size_t)b2 * NW + wl] >> sh) & 0xff;
        }
    }
    grid.sync();

    // ---- P5: bucket scatter (dst blocks only) ----
    if (b >= 128) return;
    for (int w = tid; w < NW; w += 256) hw[w] = 0;
    __syncthreads();
    const int* bt = basetab + (size_t)b * NN;
    for (int e = e0 + tid; e < e1; e += 256) {
        int s = ei[e], d = ei[NE + e];
        int sh = (d & 3) * 8;
        unsigned int old = atomicAdd(&hw[d >> 2], 1u << sh);
        int local = (old >> sh) & 0xff;
        col[bt[d] + local] = s;
    }
}

// ---- MFMA GEMM: Cm[64x128 bf16] = rowscale(A[64x128]) @ B, BT[128][128] bf16 ----
template <bool ABF>
__global__ __launch_bounds__(256) void k_gemm_bf(const void* __restrict__ Ap,
                                                 const float* __restrict__ rs,
                                                 const unsigned short* __restrict__ BT,
                                                 unsigned short* __restrict__ Cm) {
    __shared__ unsigned short As[64][136];
    __shared__ unsigned short Bs[128][136];
    int tid = threadIdx.x, lane = tid & 63, wave = tid >> 6;
    int quad = lane >> 4, l16 = lane & 15;
    int row0 = blockIdx.x * 64;

    if (ABF) {
        const unsigned short* A = (const unsigned short*)Ap;
#pragma unroll
        for (int p = 0; p < 4; ++p) {
            int fid = tid + p * 256;
            int r = fid >> 4, c = fid & 15;
            int gr = row0 + r; if (gr > NN - 1) gr = NN - 1;
            *(uint4*)&As[r][c * 8] = *(const uint4*)(A + (size_t)gr * DD + c * 8);
        }
    } else {
        const float* A = (const float*)Ap;
#pragma unroll
        for (int p = 0; p < 8; ++p) {
            int fid = tid + p * 256;
            int r = fid >> 5, c = fid & 31;
            int gr = row0 + r; if (gr > NN - 1) gr = NN - 1;
            float4 v = *(const float4*)(A + (size_t)gr * DD + c * 4);
            ushort4 u;
            u.x = f2bf(v.x); u.y = f2bf(v.y); u.z = f2bf(v.z); u.w = f2bf(v.w);
            *(ushort4*)&As[r][c * 4] = u;
        }
    }
#pragma unroll
    for (int p = 0; p < 8; ++p) {
        int fid = tid + p * 256;
        int r = fid >> 4, c = fid & 15;
        *(uint4*)&Bs[r][c * 8] = *(const uint4*)(BT + (size_t)r * DD + c * 8);
    }
    __syncthreads();

    short8 af[4];
#pragma unroll
    for (int ks = 0; ks < 4; ++ks)
        af[ks] = *(const short8*)&As[wave * 16 + l16][ks * 32 + quad * 8];
    floatx4 acc[8];
#pragma unroll
    for (int nt = 0; nt < 8; ++nt) acc[nt] = (floatx4){0.f, 0.f, 0.f, 0.f};
#pragma unroll
    for (int ks = 0; ks < 4; ++ks) {
#pragma unroll
        for (int nt = 0; nt < 8; ++nt) {
            short8 bf = *(const short8*)&Bs[nt * 16 + l16][ks * 32 + quad * 8];
            acc[nt] = __builtin_amdgcn_mfma_f32_16x16x32_bf16(af[ks], bf, acc[nt], 0, 0, 0);
        }
    }
    int rbase = row0 + wave * 16 + quad * 4;
#pragma unroll
    for (int r = 0; r < 4; ++r) {
        int gr = rbase + r;
        if (gr < NN) {
            float s = rs[gr];
#pragma unroll
            for (int nt = 0; nt < 8; ++nt)
                Cm[(size_t)gr * DD + nt * 16 + l16] = f2bf(acc[nt][r] * s);
        }
    }
}

// ---- CSR aggregate + fused finalize: H[n] = bf16((sum T[s]) * r_in[n] + b) ----
// 16 lanes/node, uint4/lane; 4 gathers in flight for memory-level parallelism.
__global__ __launch_bounds__(256) void k_aggregate(const unsigned short* __restrict__ T,
                                                   const int* __restrict__ row_ptr,
                                                   const int* __restrict__ col,
                                                   const float* __restrict__ r_in,
                                                   const float* __restrict__ b,
                                                   unsigned short* __restrict__ H) {
    int wave = threadIdx.x >> 6, lane = threadIdx.x & 63;
    int sub = lane >> 4, l16 = lane & 15;
    int node = blockIdx.x * 16 + wave * 4 + sub;
    if (node >= NN) return;
    int beg = row_ptr[node], end = row_ptr[node + 1];
    float a0 = 0.f, a1 = 0.f, a2 = 0.f, a3 = 0.f, a4 = 0.f, a5 = 0.f, a6 = 0.f, a7 = 0.f;
    for (int base = beg; base < end; base += 16) {
        int m = end - base; if (m > 16) m = 16;
        int myidx = (l16 < m) ? col[base + l16] : 0;
        int j = 0;
        for (; j + 4 <= m; j += 4) {
            int s0 = __shfl(myidx, (sub << 4) | j);
            int s1 = __shfl(myidx, (sub << 4) | (j + 1));
            int s2 = __shfl(myidx, (sub << 4) | (j + 2));
            int s3 = __shfl(myidx, (sub << 4) | (j + 3));
            uint4 v0 = *(const uint4*)(T + (size_t)s0 * DD + l16 * 8);
            uint4 v1 = *(const uint4*)(T + (size_t)s1 * DD + l16 * 8);
            uint4 v2 = *(const uint4*)(T + (size_t)s2 * DD + l16 * 8);
            uint4 v3 = *(const uint4*)(T + (size_t)s3 * DD + l16 * 8);
            a0 += bf2f(v0.x & 0xffff) + bf2f(v1.x & 0xffff) + bf2f(v2.x & 0xffff) + bf2f(v3.x & 0xffff);
            a1 += bf2f(v0.x >> 16)    + bf2f(v1.x >> 16)    + bf2f(v2.x >> 16)    + bf2f(v3.x >> 16);
            a2 += bf2f(v0.y & 0xffff) + bf2f(v1.y & 0xffff) + bf2f(v2.y & 0xffff) + bf2f(v3.y & 0xffff);
            a3 += bf2f(v0.y >> 16)    + bf2f(v1.y >> 16)    + bf2f(v2.y >> 16)    + bf2f(v3.y >> 16);
            a4 += bf2f(v0.z & 0xffff) + bf2f(v1.z & 0xffff) + bf2f(v2.z & 0xffff) + bf2f(v3.z & 0xffff);
            a5 += bf2f(v0.z >> 16)    + bf2f(v1.z >> 16)    + bf2f(v2.z >> 16)    + bf2f(v3.z >> 16);
            a6 += bf2f(v0.w & 0xffff) + bf2f(v1.w & 0xffff) + bf2f(v2.w & 0xffff) + bf2f(v3.w & 0xffff);
            a7 += bf2f(v0.w >> 16)    + bf2f(v1.w >> 16)    + bf2f(v2.w >> 16)    + bf2f(v3.w >> 16);
        }
        for (; j < m; ++j) {
            int s0 = __shfl(myidx, (sub << 4) | j);
            uint4 v0 = *(const uint4*)(T + (size_t)s0 * DD + l16 * 8);
            a0 += bf2f(v0.x & 0xffff); a1 += bf2f(v0.x >> 16);
            a2 += bf2f(v0.y & 0xffff); a3 += bf2f(v0.y >> 16);
            a4 += bf2f(v0.z & 0xffff); a5 += bf2f(v0.z >> 16);
            a6 += bf2f(v0.w & 0xffff); a7 += bf2f(v0.w >> 16);
        }
    }
    float rv = r_in[node];
    float4 bl = *(const float4*)(b + l16 * 8);
    float4 bh = *(const float4*)(b + l16 * 8 + 4);
    uint4 w;
    w.x = (unsigned int)f2bf(a0 * rv + bl.x) | ((unsigned int)f2bf(a1 * rv + bl.y) << 16);
    w.y = (unsigned int)f2bf(a2 * rv + bl.z) | ((unsigned int)f2bf(a3 * rv + bl.w) << 16);
    w.z = (unsigned int)f2bf(a4 * rv + bh.x) | ((unsigned int)f2bf(a5 * rv + bh.y) << 16);
    w.w = (unsigned int)f2bf(a6 * rv + bh.z) | ((unsigned int)f2bf(a7 * rv + bh.w) << 16);
    *(uint4*)(H + (size_t)node * DD + l16 * 8) = w;
}

// ---- MFMA MLP: P[n] = softmax(relu(h2[n]@dW + db)@oW + ob) ----
__global__ __launch_bounds__(256) void k_mlp_mfma(const unsigned short* __restrict__ H2,
                                                  const unsigned short* __restrict__ BTd,
                                                  const float* __restrict__ db,
                                                  const float* __restrict__ oW,
                                                  const float* __restrict__ ob,
                                                  float* __restrict__ P) {
    __shared__ unsigned short As[64][136];
    __shared__ unsigned short Bs[128][136];
    int tid = threadIdx.x, lane = tid & 63, wave = tid >> 6;
    int quad = lane >> 4, l16 = lane & 15;
    int row0 = blockIdx.x * 64;
#pragma unroll
    for (int p = 0; p < 4; ++p) {
        int fid = tid + p * 256;
        int r = fid >> 4, c = fid & 15;
        int gr = row0 + r; if (gr > NN - 1) gr = NN - 1;
        *(uint4*)&As[r][c * 8] = *(const uint4*)(H2 + (size_t)gr * DD + c * 8);
    }
    short8 af[4];
    floatx4 acc[16];
#pragma unroll
    for (int i = 0; i < 16; ++i) acc[i] = (floatx4){0.f, 0.f, 0.f, 0.f};

    for (int ch = 0; ch < 2; ++ch) {
        __syncthreads();
#pragma unroll
        for (int p = 0; p < 8; ++p) {
            int fid = tid + p * 256;
            int r = fid >> 4, c = fid & 15;
            *(uint4*)&Bs[r][c * 8] = *(const uint4*)(BTd + (size_t)(ch * 128 + r) * DD + c * 8);
        }
        __syncthreads();
        if (ch == 0) {
#pragma unroll
            for (int ks = 0; ks < 4; ++ks)
                af[ks] = *(const short8*)&As[wave * 16 + l16][ks * 32 + quad * 8];
        }
#pragma unroll
        for (int ks = 0; ks < 4; ++ks) {
#pragma unroll
            for (int nt = 0; nt < 8; ++nt) {
                short8 bf = *(const short8*)&Bs[nt * 16 + l16][ks * 32 + quad * 8];
                acc[ch * 8 + nt] =
                    __builtin_amdgcn_mfma_f32_16x16x32_bf16(af[ks], bf, acc[ch * 8 + nt], 0, 0, 0);
            }
        }
    }
    int rbase = row0 + wave * 16 + quad * 4;
#pragma unroll
    for (int r = 0; r < 4; ++r) {
        float p0 = 0.f, p1 = 0.f;
#pragma unroll
        for (int ch = 0; ch < 2; ++ch) {
#pragma unroll
            for (int nt = 0; nt < 8; ++nt) {
                int colc = ch * 128 + nt * 16 + l16;
                float h = acc[ch * 8 + nt][r] + db[colc];
                h = fmaxf(h, 0.f);
                p0 += h * oW[2 * colc];
                p1 += h * oW[2 * colc + 1];
            }
        }
#pragma unroll
        for (int m = 8; m >= 1; m >>= 1) {
            p0 += __shfl_xor(p0, m, 16);
            p1 += __shfl_xor(p1, m, 16);
        }
        if (l16 == 0) {
            int gr = rbase + r;
            if (gr < NN) {
                float l0 = p0 + ob[0], l1 = p1 + ob[1];
                float mx = fmaxf(l0, l1);
                float e0 = __expf(l0 - mx), e1 = __expf(l1 - mx);
                float inv = 1.f / (e0 + e1);
                float2 pr = {e0 * inv, e1 * inv};
                *(float2*)(P + 2 * gr) = pr;
            }
        }
    }
}

// ---- final gather ----
__global__ void k_gather(const int* __restrict__ sidx, const int* __restrict__ oe,
                         const float* __restrict__ P, float* __restrict__ out) {
    int i = blockIdx.x * 256 + threadIdx.x;
    if (i >= NS) return;
    int node = oe[sidx[i]];
    float2 v = *(const float2*)(P + 2 * node);
    *(float2*)(out + 2 * i) = v;
}

extern "C" void kernel_launch(void* const* d_in, const int* in_sizes, int n_in,
                              void* d_out, int out_size, void* d_ws, size_t ws_size,
                              hipStream_t stream) {
    const float* node_state = (const float*)d_in[0];
    const int* ei   = (const int*)d_in[1];
    const int* oe   = (const int*)d_in[2];
    const int* sidx = (const int*)d_in[3];
    const float* W1 = (const float*)d_in[4];
    const float* b1 = (const float*)d_in[5];
    const float* W2 = (const float*)d_in[6];
    const float* b2 = (const float*)d_in[7];
    const float* dW = (const float*)d_in[8];
    const float* db = (const float*)d_in[9];
    const float* oW = (const float*)d_in[10];
    const float* ob = (const float*)d_in[11];
    float* out = (float*)d_out;

    char* ws = (char*)d_ws;
    size_t off = 0;
    auto carve = [&](size_t bytes) -> char* {
        char* p = ws + off;
        off = (off + bytes + 255) & ~(size_t)255;
        return p;
    };
    int*   deg_in  = (int*)carve((size_t)NN * 4);
    float* r       = (float*)carve((size_t)2 * NN * 4);
    int*   row_ptr = (int*)carve((size_t)(NN + 1) * 4);
    int*   col     = (int*)carve((size_t)NE * 4);
    unsigned int* P_hist = (unsigned int*)carve((size_t)2 * NBH * NW * 4);
    int*   basetab = (int*)carve((size_t)NBH * NN * 4);
    int*   blocksum = (int*)carve(256 * 4);
    int*   blockoff = (int*)carve(256 * 4);
    unsigned short* t   = (unsigned short*)carve((size_t)NN * DD * 2);
    unsigned short* h   = (unsigned short*)carve((size_t)NN * DD * 2);
    unsigned short* BT1 = (unsigned short*)carve((size_t)DD * DD * 2);
    unsigned short* BT2 = (unsigned short*)carve((size_t)DD * DD * 2);
    unsigned short* BTd = (unsigned short*)carve((size_t)DD * NU * 2);
    float* P = (float*)t;   // alias: t dead after second aggregate

    float* r_out = r;
    float* r_in  = r + NN;

    // CSR build + rsqrt + weight cast, one cooperative launch
    void* args[] = {(void*)&ei, (void*)&W1, (void*)&W2, (void*)&dW,
                    (void*)&BT1, (void*)&BT2, (void*)&BTd,
                    (void*)&P_hist, (void*)&deg_in, (void*)&r,
                    (void*)&row_ptr, (void*)&basetab, (void*)&col,
                    (void*)&blocksum, (void*)&blockoff};
    hipLaunchCooperativeKernel((const void*)k_csr_coop, dim3(256), dim3(256), args, 0, stream);

    // layer 1
    k_gemm_bf<false><<<NB64, 256, 0, stream>>>(node_state, r_out, BT1, t);
    k_aggregate<<<(NN + 15) / 16, 256, 0, stream>>>(t, row_ptr, col, r_in, b1, h);

    // layer 2
    k_gemm_bf<true><<<NB64, 256, 0, stream>>>(h, r_out, BT2, t);
    k_aggregate<<<(NN + 15) / 16, 256, 0, stream>>>(t, row_ptr, col, r_in, b2, h);

    // per-node MLP + softmax, then gather
    k_mlp_mfma<<<NB64, 256, 0, stream>>>(h, BTd, db, oW, ob, P);
    k_gather<<<(NS + 255) / 256, 256, 0, stream>>>(sidx, oe, P, out);
}

// Round 9
// 258.688 us; speedup vs baseline: 1.6089x; 1.6089x over previous
//
#include <hip/hip_runtime.h>

#define NN 50000
#define DD 128
#define NE 600000
#define NP 200000
#define NS 300000
#define NU 256
#define NBH 64
#define EPB 9375   // NE/NBH
#define NW 12500   // NN/4 byte-packed words
#define NB64 782   // ceil(NN/64)

typedef __attribute__((ext_vector_type(8))) short short8;
typedef __attribute__((ext_vector_type(4))) float floatx4;

__device__ inline float bf2f(unsigned int u16) {
    unsigned int x = u16 << 16;
    float f; __builtin_memcpy(&f, &x, 4); return f;
}
__device__ inline unsigned short f2bf(float f) {
    unsigned int x; __builtin_memcpy(&x, &f, 4);
    unsigned int lsb = (x >> 16) & 1u;
    x += 0x7fffu + lsb;
    return (unsigned short)(x >> 16);
}

// ---- per-block byte histograms: grid (NBH, 2); y=0 counts src, y=1 counts dst ----
__global__ __launch_bounds__(256) void k_hist(const int* __restrict__ ei,
                                              unsigned int* __restrict__ P) {
    __shared__ unsigned int hw[NW];
    int b = blockIdx.x, half = blockIdx.y, tid = threadIdx.x;
    for (int w = tid; w < NW; w += 256) hw[w] = 0;
    __syncthreads();
    const int* src = ei + (size_t)half * NE;
    int e0 = b * EPB, e1 = min(e0 + EPB, NE);
    for (int e = e0 + tid; e < e1; e += 256) {
        int s = src[e];
        atomicAdd(&hw[s >> 2], 1u << ((s & 3) * 8));
    }
    __syncthreads();
    unsigned int* Pb = P + ((size_t)half * NBH + b) * NW;
    for (int w = tid; w < NW; w += 256) Pb[w] = hw[w];
}

// ---- reduce partials -> deg_in + rsqrt for both halves; plus fused weight cast ----
// grid 256x256 = 65536 threads: first 25000 reduce; all do one weight-cast element.
__global__ void k_reduce_cast(const unsigned int* __restrict__ P, int* __restrict__ deg_in,
                              float* __restrict__ r,
                              const float* __restrict__ W1, const float* __restrict__ W2,
                              const float* __restrict__ dW, unsigned short* __restrict__ BT1,
                              unsigned short* __restrict__ BT2, unsigned short* __restrict__ BTd) {
    int gid = blockIdx.x * 256 + threadIdx.x;
    if (gid < 2 * NW) {
        int half = (gid >= NW);
        int wl = gid - half * NW;
        const unsigned int* Ph = P + (size_t)half * NBH * NW + wl;
        int c0 = 0, c1 = 0, c2 = 0, c3 = 0;
        for (int b = 0; b < NBH; ++b) {
            unsigned int v = Ph[(size_t)b * NW];
            c0 += v & 0xff; c1 += (v >> 8) & 0xff; c2 += (v >> 16) & 0xff; c3 += v >> 24;
        }
        int nb = wl * 4;
        if (half) {
            int4 d = {c0, c1, c2, c3};
            *(int4*)(deg_in + nb) = d;
        }
        float4 rr = {rsqrtf((float)max(c0, 1)), rsqrtf((float)max(c1, 1)),
                     rsqrtf((float)max(c2, 1)), rsqrtf((float)max(c3, 1))};
        *(float4*)(r + (size_t)half * NN + nb) = rr;
    }
    {
        int t = gid;
        if (t < 16384) { int rr = t >> 7, cc = t & 127; BT1[cc * 128 + rr] = f2bf(W1[t]); }
        else if (t < 32768) { int t2 = t - 16384; int rr = t2 >> 7, cc = t2 & 127; BT2[cc * 128 + rr] = f2bf(W2[t2]); }
        else if (t < 65536) { int t2 = t - 32768; int rr = t2 >> 8, cc = t2 & 255; BTd[cc * 128 + rr] = f2bf(dW[t2]); }
    }
}

// ---- single-block exclusive prefix sum (int4-wide) of deg_in -> row_ptr[NN+1] ----
__global__ __launch_bounds__(1024) void k_scan(const int* __restrict__ deg_in,
                                               int* __restrict__ row_ptr) {
    __shared__ int wsum[16];
    __shared__ int woff[16];
    __shared__ int carry_s;
    __shared__ int total_s;
    int tid = threadIdx.x, lane = tid & 63, w = tid >> 6;
    if (tid == 0) carry_s = 0;
    __syncthreads();
    for (int wb = 0; wb < NW; wb += 1024) {
        int i4 = wb + tid;
        int4 v = {0, 0, 0, 0};
        if (i4 < NW) v = *(const int4*)(deg_in + i4 * 4);
        int t0 = v.x, t1 = t0 + v.y, t2 = t1 + v.z, tot = t2 + v.w;
        int x = tot;
#pragma unroll
        for (int off = 1; off < 64; off <<= 1) {
            int y = __shfl_up(x, off);
            if (lane >= off) x += y;
        }
        if (lane == 63) wsum[w] = x;
        __syncthreads();
        if (w == 0 && lane < 16) {
            int s = wsum[lane];
            int xs = s;
#pragma unroll
            for (int off = 1; off < 16; off <<= 1) {
                int y = __shfl_up(xs, off);
                if (lane >= off) xs += y;
            }
            woff[lane] = xs - s;
            if (lane == 15) total_s = xs;
        }
        __syncthreads();
        if (i4 < NW) {
            int base = carry_s + woff[w] + x - tot;
            int4 o = {base, base + t0, base + t1, base + t2};
            *(int4*)(row_ptr + i4 * 4) = o;
        }
        __syncthreads();
        if (tid == 0) carry_s += total_s;
        __syncthreads();
    }
    if (tid == 0) row_ptr[NN] = NE;
}

// ---- per-(block,node) exclusive base offsets WITHIN row (fits in a byte) ----
__global__ void k_colscan(const unsigned int* __restrict__ Pin,
                          unsigned char* __restrict__ baseb) {
    int n = blockIdx.x * 256 + threadIdx.x;
    if (n >= NN) return;
    int wl = n >> 2, sh = (n & 3) * 8;
    int run = 0;
    for (int b = 0; b < NBH; ++b) {
        baseb[(size_t)b * NN + n] = (unsigned char)run;
        run += (Pin[(size_t)b * NW + wl] >> sh) & 0xff;
    }
}

// ---- bucket edges, no global atomics: LDS byte cursor + byte base + row_ptr ----
__global__ __launch_bounds__(256) void k_bucket2(const int* __restrict__ ei,
                                                 const int* __restrict__ row_ptr,
                                                 const unsigned char* __restrict__ baseb,
                                                 int* __restrict__ col) {
    __shared__ unsigned int cw[NW];
    int b = blockIdx.x, tid = threadIdx.x;
    for (int w = tid; w < NW; w += 256) cw[w] = 0;
    __syncthreads();
    const unsigned char* bt = baseb + (size_t)b * NN;
    int e0 = b * EPB, e1 = min(e0 + EPB, NE);
    for (int e = e0 + tid; e < e1; e += 256) {
        int s = ei[e], d = ei[NE + e];
        int sh = (d & 3) * 8;
        unsigned int old = atomicAdd(&cw[d >> 2], 1u << sh);
        int local = (old >> sh) & 0xff;
        col[row_ptr[d] + (int)bt[d] + local] = s;
    }
}

// ---- MFMA GEMM: Cm[64x128 bf16] = rowscale(A[64x128]) @ B, BT[128][128] bf16 ----
template <bool ABF>
__global__ __launch_bounds__(256) void k_gemm_bf(const void* __restrict__ Ap,
                                                 const float* __restrict__ rs,
                                                 const unsigned short* __restrict__ BT,
                                                 unsigned short* __restrict__ Cm) {
    __shared__ unsigned short As[64][136];
    __shared__ unsigned short Bs[128][136];
    int tid = threadIdx.x, lane = tid & 63, wave = tid >> 6;
    int quad = lane >> 4, l16 = lane & 15;
    int row0 = blockIdx.x * 64;

    if (ABF) {
        const unsigned short* A = (const unsigned short*)Ap;
#pragma unroll
        for (int p = 0; p < 4; ++p) {
            int fid = tid + p * 256;
            int r = fid >> 4, c = fid & 15;
            int gr = row0 + r; if (gr > NN - 1) gr = NN - 1;
            *(uint4*)&As[r][c * 8] = *(const uint4*)(A + (size_t)gr * DD + c * 8);
        }
    } else {
        const float* A = (const float*)Ap;
#pragma unroll
        for (int p = 0; p < 8; ++p) {
            int fid = tid + p * 256;
            int r = fid >> 5, c = fid & 31;
            int gr = row0 + r; if (gr > NN - 1) gr = NN - 1;
            float4 v = *(const float4*)(A + (size_t)gr * DD + c * 4);
            ushort4 u;
            u.x = f2bf(v.x); u.y = f2bf(v.y); u.z = f2bf(v.z); u.w = f2bf(v.w);
            *(ushort4*)&As[r][c * 4] = u;
        }
    }
#pragma unroll
    for (int p = 0; p < 8; ++p) {
        int fid = tid + p * 256;
        int r = fid >> 4, c = fid & 15;
        *(uint4*)&Bs[r][c * 8] = *(const uint4*)(BT + (size_t)r * DD + c * 8);
    }
    __syncthreads();

    short8 af[4];
#pragma unroll
    for (int ks = 0; ks < 4; ++ks)
        af[ks] = *(const short8*)&As[wave * 16 + l16][ks * 32 + quad * 8];
    floatx4 acc[8];
#pragma unroll
    for (int nt = 0; nt < 8; ++nt) acc[nt] = (floatx4){0.f, 0.f, 0.f, 0.f};
#pragma unroll
    for (int ks = 0; ks < 4; ++ks) {
#pragma unroll
        for (int nt = 0; nt < 8; ++nt) {
            short8 bf = *(const short8*)&Bs[nt * 16 + l16][ks * 32 + quad * 8];
            acc[nt] = __builtin_amdgcn_mfma_f32_16x16x32_bf16(af[ks], bf, acc[nt], 0, 0, 0);
        }
    }
    int rbase = row0 + wave * 16 + quad * 4;
#pragma unroll
    for (int r = 0; r < 4; ++r) {
        int gr = rbase + r;
        if (gr < NN) {
            float s = rs[gr];
#pragma unroll
            for (int nt = 0; nt < 8; ++nt)
                Cm[(size_t)gr * DD + nt * 16 + l16] = f2bf(acc[nt][r] * s);
        }
    }
}

// ---- CSR aggregate + fused finalize: H[n] = bf16((sum T[s]) * r_in[n] + b) ----
// 16 lanes/node, uint4/lane; 4 gathers in flight for memory-level parallelism.
__global__ __launch_bounds__(256) void k_aggregate(const unsigned short* __restrict__ T,
                                                   const int* __restrict__ row_ptr,
                                                   const int* __restrict__ col,
                                                   const float* __restrict__ r_in,
                                                   const float* __restrict__ b,
                                                   unsigned short* __restrict__ H) {
    int wave = threadIdx.x >> 6, lane = threadIdx.x & 63;
    int sub = lane >> 4, l16 = lane & 15;
    int node = blockIdx.x * 16 + wave * 4 + sub;
    if (node >= NN) return;
    int beg = row_ptr[node], end = row_ptr[node + 1];
    float a0 = 0.f, a1 = 0.f, a2 = 0.f, a3 = 0.f, a4 = 0.f, a5 = 0.f, a6 = 0.f, a7 = 0.f;
    for (int base = beg; base < end; base += 16) {
        int m = end - base; if (m > 16) m = 16;
        int myidx = (l16 < m) ? col[base + l16] : 0;
        int j = 0;
        for (; j + 4 <= m; j += 4) {
            int s0 = __shfl(myidx, (sub << 4) | j);
            int s1 = __shfl(myidx, (sub << 4) | (j + 1));
            int s2 = __shfl(myidx, (sub << 4) | (j + 2));
            int s3 = __shfl(myidx, (sub << 4) | (j + 3));
            uint4 v0 = *(const uint4*)(T + (size_t)s0 * DD + l16 * 8);
            uint4 v1 = *(const uint4*)(T + (size_t)s1 * DD + l16 * 8);
            uint4 v2 = *(const uint4*)(T + (size_t)s2 * DD + l16 * 8);
            uint4 v3 = *(const uint4*)(T + (size_t)s3 * DD + l16 * 8);
            a0 += bf2f(v0.x & 0xffff) + bf2f(v1.x & 0xffff) + bf2f(v2.x & 0xffff) + bf2f(v3.x & 0xffff);
            a1 += bf2f(v0.x >> 16)    + bf2f(v1.x >> 16)    + bf2f(v2.x >> 16)    + bf2f(v3.x >> 16);
            a2 += bf2f(v0.y & 0xffff) + bf2f(v1.y & 0xffff) + bf2f(v2.y & 0xffff) + bf2f(v3.y & 0xffff);
            a3 += bf2f(v0.y >> 16)    + bf2f(v1.y >> 16)    + bf2f(v2.y >> 16)    + bf2f(v3.y >> 16);
            a4 += bf2f(v0.z & 0xffff) + bf2f(v1.z & 0xffff) + bf2f(v2.z & 0xffff) + bf2f(v3.z & 0xffff);
            a5 += bf2f(v0.z >> 16)    + bf2f(v1.z >> 16)    + bf2f(v2.z >> 16)    + bf2f(v3.z >> 16);
            a6 += bf2f(v0.w & 0xffff) + bf2f(v1.w & 0xffff) + bf2f(v2.w & 0xffff) + bf2f(v3.w & 0xffff);
            a7 += bf2f(v0.w >> 16)    + bf2f(v1.w >> 16)    + bf2f(v2.w >> 16)    + bf2f(v3.w >> 16);
        }
        for (; j < m; ++j) {
            int s0 = __shfl(myidx, (sub << 4) | j);
            uint4 v0 = *(const uint4*)(T + (size_t)s0 * DD + l16 * 8);
            a0 += bf2f(v0.x & 0xffff); a1 += bf2f(v0.x >> 16);
            a2 += bf2f(v0.y & 0xffff); a3 += bf2f(v0.y >> 16);
            a4 += bf2f(v0.z & 0xffff); a5 += bf2f(v0.z >> 16);
            a6 += bf2f(v0.w & 0xffff); a7 += bf2f(v0.w >> 16);
        }
    }
    float rv = r_in[node];
    float4 bl = *(const float4*)(b + l16 * 8);
    float4 bh = *(const float4*)(b + l16 * 8 + 4);
    uint4 w;
    w.x = (unsigned int)f2bf(a0 * rv + bl.x) | ((unsigned int)f2bf(a1 * rv + bl.y) << 16);
    w.y = (unsigned int)f2bf(a2 * rv + bl.z) | ((unsigned int)f2bf(a3 * rv + bl.w) << 16);
    w.z = (unsigned int)f2bf(a4 * rv + bh.x) | ((unsigned int)f2bf(a5 * rv + bh.y) << 16);
    w.w = (unsigned int)f2bf(a6 * rv + bh.z) | ((unsigned int)f2bf(a7 * rv + bh.w) << 16);
    *(uint4*)(H + (size_t)node * DD + l16 * 8) = w;
}

// ---- MFMA MLP: P[n] = softmax(relu(h2[n]@dW + db)@oW + ob) ----
__global__ __launch_bounds__(256) void k_mlp_mfma(const unsigned short* __restrict__ H2,
                                                  const unsigned short* __restrict__ BTd,
                                                  const float* __restrict__ db,
                                                  const float* __restrict__ oW,
                                                  const float* __restrict__ ob,
                                                  float* __restrict__ P) {
    __shared__ unsigned short As[64][136];
    __shared__ unsigned short Bs[128][136];
    int tid = threadIdx.x, lane = tid & 63, wave = tid >> 6;
    int quad = lane >> 4, l16 = lane & 15;
    int row0 = blockIdx.x * 64;
#pragma unroll
    for (int p = 0; p < 4; ++p) {
        int fid = tid + p * 256;
        int r = fid >> 4, c = fid & 15;
        int gr = row0 + r; if (gr > NN - 1) gr = NN - 1;
        *(uint4*)&As[r][c * 8] = *(const uint4*)(H2 + (size_t)gr * DD + c * 8);
    }
    short8 af[4];
    floatx4 acc[16];
#pragma unroll
    for (int i = 0; i < 16; ++i) acc[i] = (floatx4){0.f, 0.f, 0.f, 0.f};

    for (int ch = 0; ch < 2; ++ch) {
        __syncthreads();
#pragma unroll
        for (int p = 0; p < 8; ++p) {
            int fid = tid + p * 256;
            int r = fid >> 4, c = fid & 15;
            *(uint4*)&Bs[r][c * 8] = *(const uint4*)(BTd + (size_t)(ch * 128 + r) * DD + c * 8);
        }
        __syncthreads();
        if (ch == 0) {
#pragma unroll
            for (int ks = 0; ks < 4; ++ks)
                af[ks] = *(const short8*)&As[wave * 16 + l16][ks * 32 + quad * 8];
        }
#pragma unroll
        for (int ks = 0; ks < 4; ++ks) {
#pragma unroll
            for (int nt = 0; nt < 8; ++nt) {
                short8 bf = *(const short8*)&Bs[nt * 16 + l16][ks * 32 + quad * 8];
                acc[ch * 8 + nt] =
                    __builtin_amdgcn_mfma_f32_16x16x32_bf16(af[ks], bf, acc[ch * 8 + nt], 0, 0, 0);
            }
        }
    }
    int rbase = row0 + wave * 16 + quad * 4;
#pragma unroll
    for (int r = 0; r < 4; ++r) {
        float p0 = 0.f, p1 = 0.f;
#pragma unroll
        for (int ch = 0; ch < 2; ++ch) {
#pragma unroll
            for (int nt = 0; nt < 8; ++nt) {
                int colc = ch * 128 + nt * 16 + l16;
                float h = acc[ch * 8 + nt][r] + db[colc];
                h = fmaxf(h, 0.f);
                p0 += h * oW[2 * colc];
                p1 += h * oW[2 * colc + 1];
            }
        }
#pragma unroll
        for (int m = 8; m >= 1; m >>= 1) {
            p0 += __shfl_xor(p0, m, 16);
            p1 += __shfl_xor(p1, m, 16);
        }
        if (l16 == 0) {
            int gr = rbase + r;
            if (gr < NN) {
                float l0 = p0 + ob[0], l1 = p1 + ob[1];
                float mx = fmaxf(l0, l1);
                float e0 = __expf(l0 - mx), e1 = __expf(l1 - mx);
                float inv = 1.f / (e0 + e1);
                float2 pr = {e0 * inv, e1 * inv};
                *(float2*)(P + 2 * gr) = pr;
            }
        }
    }
}

// ---- final gather ----
__global__ void k_gather(const int* __restrict__ sidx, const int* __restrict__ oe,
                         const float* __restrict__ P, float* __restrict__ out) {
    int i = blockIdx.x * 256 + threadIdx.x;
    if (i >= NS) return;
    int node = oe[sidx[i]];
    float2 v = *(const float2*)(P + 2 * node);
    *(float2*)(out + 2 * i) = v;
}

extern "C" void kernel_launch(void* const* d_in, const int* in_sizes, int n_in,
                              void* d_out, int out_size, void* d_ws, size_t ws_size,
                              hipStream_t stream) {
    const float* node_state = (const float*)d_in[0];
    const int* ei   = (const int*)d_in[1];
    const int* oe   = (const int*)d_in[2];
    const int* sidx = (const int*)d_in[3];
    const float* W1 = (const float*)d_in[4];
    const float* b1 = (const float*)d_in[5];
    const float* W2 = (const float*)d_in[6];
    const float* b2 = (const float*)d_in[7];
    const float* dW = (const float*)d_in[8];
    const float* db = (const float*)d_in[9];
    const float* oW = (const float*)d_in[10];
    const float* ob = (const float*)d_in[11];
    float* out = (float*)d_out;

    char* ws = (char*)d_ws;
    size_t off = 0;
    auto carve = [&](size_t bytes) -> char* {
        char* p = ws + off;
        off = (off + bytes + 255) & ~(size_t)255;
        return p;
    };
    int*   deg_in  = (int*)carve((size_t)NN * 4);
    float* r       = (float*)carve((size_t)2 * NN * 4);
    int*   row_ptr = (int*)carve((size_t)(NN + 1) * 4);
    int*   col     = (int*)carve((size_t)NE * 4);
    unsigned int* P_hist = (unsigned int*)carve((size_t)2 * NBH * NW * 4);
    unsigned char* baseb = (unsigned char*)carve((size_t)NBH * NN);
    unsigned short* t   = (unsigned short*)carve((size_t)NN * DD * 2);
    unsigned short* h   = (unsigned short*)carve((size_t)NN * DD * 2);
    unsigned short* BT1 = (unsigned short*)carve((size_t)DD * DD * 2);
    unsigned short* BT2 = (unsigned short*)carve((size_t)DD * DD * 2);
    unsigned short* BTd = (unsigned short*)carve((size_t)DD * NU * 2);
    float* P = (float*)t;   // alias: t dead after second aggregate

    float* r_out = r;
    float* r_in  = r + NN;

    // CSR build — no global atomics
    k_hist<<<dim3(NBH, 2), 256, 0, stream>>>(ei, P_hist);
    k_reduce_cast<<<256, 256, 0, stream>>>(P_hist, deg_in, r, W1, W2, dW, BT1, BT2, BTd);
    k_scan<<<1, 1024, 0, stream>>>(deg_in, row_ptr);
    k_colscan<<<(NN + 255) / 256, 256, 0, stream>>>(P_hist + (size_t)NBH * NW, baseb);
    k_bucket2<<<NBH, 256, 0, stream>>>(ei, row_ptr, baseb, col);

    // layer 1
    k_gemm_bf<false><<<NB64, 256, 0, stream>>>(node_state, r_out, BT1, t);
    k_aggregate<<<(NN + 15) / 16, 256, 0, stream>>>(t, row_ptr, col, r_in, b1, h);

    // layer 2
    k_gemm_bf<true><<<NB64, 256, 0, stream>>>(h, r_out, BT2, t);
    k_aggregate<<<(NN + 15) / 16, 256, 0, stream>>>(t, row_ptr, col, r_in, b2, h);

    // per-node MLP + softmax, then gather
    k_mlp_mfma<<<NB64, 256, 0, stream>>>(h, BTd, db, oW, ob, P);
    k_gather<<<(NS + 255) / 256, 256, 0, stream>>>(sidx, oe, P, out);
}

// Round 10
// 248.264 us; speedup vs baseline: 1.6765x; 1.0420x over previous
//
#include <hip/hip_runtime.h>

#define NN 50000
#define DD 128
#define NE 600000
#define NP 200000
#define NS 300000
#define NU 256
#define NBH 64
#define EPB 9375    // NE/NBH
#define NW 12500    // NN/4 byte-packed words
#define NB64 782    // ceil(NN/64)
#define NSCAN 49    // ceil(NW/256) blocks own the row_ptr scan

typedef __attribute__((ext_vector_type(8))) short short8;
typedef __attribute__((ext_vector_type(4))) float floatx4;

__device__ inline float bf2f(unsigned int u16) {
    unsigned int x = u16 << 16;
    float f; __builtin_memcpy(&f, &x, 4); return f;
}
__device__ inline unsigned short f2bf(float f) {
    unsigned int x; __builtin_memcpy(&x, &f, 4);
    unsigned int lsb = (x >> 16) & 1u;
    x += 0x7fffu + lsb;
    return (unsigned short)(x >> 16);
}

// ---- per-block byte histograms: grid (NBH, 2); y=0 counts src, y=1 counts dst ----
// also zeroes the lookback status array (consumed by k_mid, stream-ordered).
__global__ __launch_bounds__(256) void k_hist(const int* __restrict__ ei,
                                              unsigned int* __restrict__ P,
                                              unsigned long long* __restrict__ status) {
    __shared__ unsigned int hw[NW];
    int b = blockIdx.x, half = blockIdx.y, tid = threadIdx.x;
    if (b == 0 && half == 0 && tid < 64) status[tid] = 0ull;
    for (int w = tid; w < NW; w += 256) hw[w] = 0;
    __syncthreads();
    const int* src = ei + (size_t)half * NE;
    int e0 = b * EPB, e1 = min(e0 + EPB, NE);
    for (int e = e0 + tid; e < e1; e += 256) {
        int s = src[e];
        atomicAdd(&hw[s >> 2], 1u << ((s & 3) * 8));
    }
    __syncthreads();
    unsigned int* Pb = P + ((size_t)half * NBH + b) * NW;
    for (int w = tid; w < NW; w += 256) Pb[w] = hw[w];
}

// ---- fused mid-chain: reduce+rsqrt, weight cast, row_ptr scan (decoupled
// lookback over 49 block partials), colscan byte-bases. One dispatch. ----
__global__ __launch_bounds__(256) void k_mid(
    const unsigned int* __restrict__ P_hist, float* __restrict__ r,
    const float* __restrict__ W1, const float* __restrict__ W2, const float* __restrict__ dW,
    unsigned short* __restrict__ BT1, unsigned short* __restrict__ BT2,
    unsigned short* __restrict__ BTd,
    int* __restrict__ row_ptr, unsigned char* __restrict__ baseb,
    unsigned long long* __restrict__ status)
{
    int b = blockIdx.x, tid = threadIdx.x, lane = tid & 63, w = tid >> 6;
    int gid = b * 256 + tid;

    // ---- phase A: reduce histogram columns -> counts + rsqrt ----
    int4 v = {0, 0, 0, 0};
    if (gid < NW) {                          // dst half: keep counts for scan, write r_in
        const unsigned int* Ph = P_hist + (size_t)NBH * NW + gid;
        int c0 = 0, c1 = 0, c2 = 0, c3 = 0;
        for (int b2 = 0; b2 < NBH; ++b2) {
            unsigned int x = Ph[(size_t)b2 * NW];
            c0 += x & 0xff; c1 += (x >> 8) & 0xff; c2 += (x >> 16) & 0xff; c3 += x >> 24;
        }
        v = (int4){c0, c1, c2, c3};
        float4 rr = {rsqrtf((float)max(c0, 1)), rsqrtf((float)max(c1, 1)),
                     rsqrtf((float)max(c2, 1)), rsqrtf((float)max(c3, 1))};
        *(float4*)(r + NN + gid * 4) = rr;
    } else if (gid < 2 * NW) {               // src half: write r_out
        int wl = gid - NW;
        const unsigned int* Ph = P_hist + wl;
        int c0 = 0, c1 = 0, c2 = 0, c3 = 0;
        for (int b2 = 0; b2 < NBH; ++b2) {
            unsigned int x = Ph[(size_t)b2 * NW];
            c0 += x & 0xff; c1 += (x >> 8) & 0xff; c2 += (x >> 16) & 0xff; c3 += x >> 24;
        }
        float4 rr = {rsqrtf((float)max(c0, 1)), rsqrtf((float)max(c1, 1)),
                     rsqrtf((float)max(c2, 1)), rsqrtf((float)max(c3, 1))};
        *(float4*)(r + wl * 4) = rr;
    }

    // ---- phase B: weight transpose + bf16 cast ----
    {
        int t = gid;
        if (t < 16384) { int rr = t >> 7, cc = t & 127; BT1[cc * 128 + rr] = f2bf(W1[t]); }
        else if (t < 32768) { int t2 = t - 16384; int rr = t2 >> 7, cc = t2 & 127; BT2[cc * 128 + rr] = f2bf(W2[t2]); }
        else if (t < 65536) { int t2 = t - 32768; int rr = t2 >> 8, cc = t2 & 255; BTd[cc * 128 + rr] = f2bf(dW[t2]); }
    }

    // ---- phase C: scan blocks (0..48) build row_ptr via decoupled lookback ----
    if (b < NSCAN) {
        __shared__ int wsum[4];
        __shared__ long long sbase;
        int tot = v.x + v.y + v.z + v.w;
        int x = tot;
#pragma unroll
        for (int off = 1; off < 64; off <<= 1) {
            int y = __shfl_up(x, off);
            if (lane >= off) x += y;
        }
        if (lane == 63) wsum[w] = x;
        __syncthreads();
        int woff = 0;
#pragma unroll
        for (int i = 0; i < 4; ++i) if (i < w) woff += wsum[i];
        if (tid == 0) {
            int btot = wsum[0] + wsum[1] + wsum[2] + wsum[3];
            if (b == 0) {
                sbase = 0;
                __threadfence();
                atomicExch(&status[0], (2ull << 62) | (unsigned long long)btot);
            } else {
                __threadfence();
                atomicExch(&status[b], (1ull << 62) | (unsigned long long)btot);
                long long run = 0; int j = b - 1;
                while (true) {
                    unsigned long long s;
                    do { s = atomicAdd(&status[j], 0ull); } while (s == 0ull);
                    run += (long long)(s & 0x3fffffffffffffffull);
                    if ((s >> 62) == 2ull) break;
                    --j;
                }
                sbase = run;
                __threadfence();
                atomicExch(&status[b], (2ull << 62) | (unsigned long long)(run + btot));
            }
        }
        __syncthreads();
        if (gid < NW) {
            int base = (int)sbase + woff + (x - tot);
            int4 o = {base, base + v.x, base + v.x + v.y, base + v.x + v.y + v.z};
            *(int4*)(row_ptr + gid * 4) = o;
        }
        if (b == 0 && tid == 0) row_ptr[NN] = NE;
    }

    // ---- phase D: colscan byte-bases (blocks NSCAN..NSCAN+195) ----
    int cb = b - NSCAN;
    if (cb >= 0 && cb < 196) {
        int n = cb * 256 + tid;
        if (n < NN) {
            int wl = n >> 2, sh = (n & 3) * 8;
            int run = 0;
            const unsigned int* Pd = P_hist + (size_t)NBH * NW;
            for (int b2 = 0; b2 < NBH; ++b2) {
                baseb[(size_t)b2 * NN + n] = (unsigned char)run;
                run += (Pd[(size_t)b2 * NW + wl] >> sh) & 0xff;
            }
        }
    }
}

// ---- bucket edges, no global atomics: LDS byte cursor + byte base + row_ptr ----
__global__ __launch_bounds__(256) void k_bucket2(const int* __restrict__ ei,
                                                 const int* __restrict__ row_ptr,
                                                 const unsigned char* __restrict__ baseb,
                                                 int* __restrict__ col) {
    __shared__ unsigned int cw[NW];
    int b = blockIdx.x, tid = threadIdx.x;
    for (int w = tid; w < NW; w += 256) cw[w] = 0;
    __syncthreads();
    const unsigned char* bt = baseb + (size_t)b * NN;
    int e0 = b * EPB, e1 = min(e0 + EPB, NE);
    for (int e = e0 + tid; e < e1; e += 256) {
        int s = ei[e], d = ei[NE + e];
        int sh = (d & 3) * 8;
        unsigned int old = atomicAdd(&cw[d >> 2], 1u << sh);
        int local = (old >> sh) & 0xff;
        col[row_ptr[d] + (int)bt[d] + local] = s;
    }
}

// ---- MFMA GEMM: Cm[64x128 bf16] = rowscale(A[64x128]) @ B, BT[128][128] bf16 ----
template <bool ABF>
__global__ __launch_bounds__(256) void k_gemm_bf(const void* __restrict__ Ap,
                                                 const float* __restrict__ rs,
                                                 const unsigned short* __restrict__ BT,
                                                 unsigned short* __restrict__ Cm) {
    __shared__ unsigned short As[64][136];
    __shared__ unsigned short Bs[128][136];
    int tid = threadIdx.x, lane = tid & 63, wave = tid >> 6;
    int quad = lane >> 4, l16 = lane & 15;
    int row0 = blockIdx.x * 64;

    if (ABF) {
        const unsigned short* A = (const unsigned short*)Ap;
#pragma unroll
        for (int p = 0; p < 4; ++p) {
            int fid = tid + p * 256;
            int r = fid >> 4, c = fid & 15;
            int gr = row0 + r; if (gr > NN - 1) gr = NN - 1;
            *(uint4*)&As[r][c * 8] = *(const uint4*)(A + (size_t)gr * DD + c * 8);
        }
    } else {
        const float* A = (const float*)Ap;
#pragma unroll
        for (int p = 0; p < 8; ++p) {
            int fid = tid + p * 256;
            int r = fid >> 5, c = fid & 31;
            int gr = row0 + r; if (gr > NN - 1) gr = NN - 1;
            float4 v = *(const float4*)(A + (size_t)gr * DD + c * 4);
            ushort4 u;
            u.x = f2bf(v.x); u.y = f2bf(v.y); u.z = f2bf(v.z); u.w = f2bf(v.w);
            *(ushort4*)&As[r][c * 4] = u;
        }
    }
#pragma unroll
    for (int p = 0; p < 8; ++p) {
        int fid = tid + p * 256;
        int r = fid >> 4, c = fid & 15;
        *(uint4*)&Bs[r][c * 8] = *(const uint4*)(BT + (size_t)r * DD + c * 8);
    }
    __syncthreads();

    short8 af[4];
#pragma unroll
    for (int ks = 0; ks < 4; ++ks)
        af[ks] = *(const short8*)&As[wave * 16 + l16][ks * 32 + quad * 8];
    floatx4 acc[8];
#pragma unroll
    for (int nt = 0; nt < 8; ++nt) acc[nt] = (floatx4){0.f, 0.f, 0.f, 0.f};
#pragma unroll
    for (int ks = 0; ks < 4; ++ks) {
#pragma unroll
        for (int nt = 0; nt < 8; ++nt) {
            short8 bf = *(const short8*)&Bs[nt * 16 + l16][ks * 32 + quad * 8];
            acc[nt] = __builtin_amdgcn_mfma_f32_16x16x32_bf16(af[ks], bf, acc[nt], 0, 0, 0);
        }
    }
    int rbase = row0 + wave * 16 + quad * 4;
#pragma unroll
    for (int r = 0; r < 4; ++r) {
        int gr = rbase + r;
        if (gr < NN) {
            float s = rs[gr];
#pragma unroll
            for (int nt = 0; nt < 8; ++nt)
                Cm[(size_t)gr * DD + nt * 16 + l16] = f2bf(acc[nt][r] * s);
        }
    }
}

// ---- CSR aggregate + fused finalize: H[n] = bf16((sum T[s]) * r_in[n] + b) ----
// 16 lanes/node, uint4/lane; 4 gathers in flight for memory-level parallelism.
__global__ __launch_bounds__(256) void k_aggregate(const unsigned short* __restrict__ T,
                                                   const int* __restrict__ row_ptr,
                                                   const int* __restrict__ col,
                                                   const float* __restrict__ r_in,
                                                   const float* __restrict__ b,
                                                   unsigned short* __restrict__ H) {
    int wave = threadIdx.x >> 6, lane = threadIdx.x & 63;
    int sub = lane >> 4, l16 = lane & 15;
    int node = blockIdx.x * 16 + wave * 4 + sub;
    if (node >= NN) return;
    int beg = row_ptr[node], end = row_ptr[node + 1];
    float a0 = 0.f, a1 = 0.f, a2 = 0.f, a3 = 0.f, a4 = 0.f, a5 = 0.f, a6 = 0.f, a7 = 0.f;
    for (int base = beg; base < end; base += 16) {
        int m = end - base; if (m > 16) m = 16;
        int myidx = (l16 < m) ? col[base + l16] : 0;
        int j = 0;
        for (; j + 4 <= m; j += 4) {
            int s0 = __shfl(myidx, (sub << 4) | j);
            int s1 = __shfl(myidx, (sub << 4) | (j + 1));
            int s2 = __shfl(myidx, (sub << 4) | (j + 2));
            int s3 = __shfl(myidx, (sub << 4) | (j + 3));
            uint4 v0 = *(const uint4*)(T + (size_t)s0 * DD + l16 * 8);
            uint4 v1 = *(const uint4*)(T + (size_t)s1 * DD + l16 * 8);
            uint4 v2 = *(const uint4*)(T + (size_t)s2 * DD + l16 * 8);
            uint4 v3 = *(const uint4*)(T + (size_t)s3 * DD + l16 * 8);
            a0 += bf2f(v0.x & 0xffff) + bf2f(v1.x & 0xffff) + bf2f(v2.x & 0xffff) + bf2f(v3.x & 0xffff);
            a1 += bf2f(v0.x >> 16)    + bf2f(v1.x >> 16)    + bf2f(v2.x >> 16)    + bf2f(v3.x >> 16);
            a2 += bf2f(v0.y & 0xffff) + bf2f(v1.y & 0xffff) + bf2f(v2.y & 0xffff) + bf2f(v3.y & 0xffff);
            a3 += bf2f(v0.y >> 16)    + bf2f(v1.y >> 16)    + bf2f(v2.y >> 16)    + bf2f(v3.y >> 16);
            a4 += bf2f(v0.z & 0xffff) + bf2f(v1.z & 0xffff) + bf2f(v2.z & 0xffff) + bf2f(v3.z & 0xffff);
            a5 += bf2f(v0.z >> 16)    + bf2f(v1.z >> 16)    + bf2f(v2.z >> 16)    + bf2f(v3.z >> 16);
            a6 += bf2f(v0.w & 0xffff) + bf2f(v1.w & 0xffff) + bf2f(v2.w & 0xffff) + bf2f(v3.w & 0xffff);
            a7 += bf2f(v0.w >> 16)    + bf2f(v1.w >> 16)    + bf2f(v2.w >> 16)    + bf2f(v3.w >> 16);
        }
        for (; j < m; ++j) {
            int s0 = __shfl(myidx, (sub << 4) | j);
            uint4 v0 = *(const uint4*)(T + (size_t)s0 * DD + l16 * 8);
            a0 += bf2f(v0.x & 0xffff); a1 += bf2f(v0.x >> 16);
            a2 += bf2f(v0.y & 0xffff); a3 += bf2f(v0.y >> 16);
            a4 += bf2f(v0.z & 0xffff); a5 += bf2f(v0.z >> 16);
            a6 += bf2f(v0.w & 0xffff); a7 += bf2f(v0.w >> 16);
        }
    }
    float rv = r_in[node];
    float4 bl = *(const float4*)(b + l16 * 8);
    float4 bh = *(const float4*)(b + l16 * 8 + 4);
    uint4 w;
    w.x = (unsigned int)f2bf(a0 * rv + bl.x) | ((unsigned int)f2bf(a1 * rv + bl.y) << 16);
    w.y = (unsigned int)f2bf(a2 * rv + bl.z) | ((unsigned int)f2bf(a3 * rv + bl.w) << 16);
    w.z = (unsigned int)f2bf(a4 * rv + bh.x) | ((unsigned int)f2bf(a5 * rv + bh.y) << 16);
    w.w = (unsigned int)f2bf(a6 * rv + bh.z) | ((unsigned int)f2bf(a7 * rv + bh.w) << 16);
    *(uint4*)(H + (size_t)node * DD + l16 * 8) = w;
}

// ---- MFMA MLP: P[n] = softmax(relu(h2[n]@dW + db)@oW + ob) ----
__global__ __launch_bounds__(256) void k_mlp_mfma(const unsigned short* __restrict__ H2,
                                                  const unsigned short* __restrict__ BTd,
                                                  const float* __restrict__ db,
                                                  const float* __restrict__ oW,
                                                  const float* __restrict__ ob,
                                                  float* __restrict__ P) {
    __shared__ unsigned short As[64][136];
    __shared__ unsigned short Bs[128][136];
    int tid = threadIdx.x, lane = tid & 63, wave = tid >> 6;
    int quad = lane >> 4, l16 = lane & 15;
    int row0 = blockIdx.x * 64;
#pragma unroll
    for (int p = 0; p < 4; ++p) {
        int fid = tid + p * 256;
        int r = fid >> 4, c = fid & 15;
        int gr = row0 + r; if (gr > NN - 1) gr = NN - 1;
        *(uint4*)&As[r][c * 8] = *(const uint4*)(H2 + (size_t)gr * DD + c * 8);
    }
    short8 af[4];
    floatx4 acc[16];
#pragma unroll
    for (int i = 0; i < 16; ++i) acc[i] = (floatx4){0.f, 0.f, 0.f, 0.f};

    for (int ch = 0; ch < 2; ++ch) {
        __syncthreads();
#pragma unroll
        for (int p = 0; p < 8; ++p) {
            int fid = tid + p * 256;
            int r = fid >> 4, c = fid & 15;
            *(uint4*)&Bs[r][c * 8] = *(const uint4*)(BTd + (size_t)(ch * 128 + r) * DD + c * 8);
        }
        __syncthreads();
        if (ch == 0) {
#pragma unroll
            for (int ks = 0; ks < 4; ++ks)
                af[ks] = *(const short8*)&As[wave * 16 + l16][ks * 32 + quad * 8];
        }
#pragma unroll
        for (int ks = 0; ks < 4; ++ks) {
#pragma unroll
            for (int nt = 0; nt < 8; ++nt) {
                short8 bf = *(const short8*)&Bs[nt * 16 + l16][ks * 32 + quad * 8];
                acc[ch * 8 + nt] =
                    __builtin_amdgcn_mfma_f32_16x16x32_bf16(af[ks], bf, acc[ch * 8 + nt], 0, 0, 0);
            }
        }
    }
    int rbase = row0 + wave * 16 + quad * 4;
#pragma unroll
    for (int r = 0; r < 4; ++r) {
        float p0 = 0.f, p1 = 0.f;
#pragma unroll
        for (int ch = 0; ch < 2; ++ch) {
#pragma unroll
            for (int nt = 0; nt < 8; ++nt) {
                int colc = ch * 128 + nt * 16 + l16;
                float h = acc[ch * 8 + nt][r] + db[colc];
                h = fmaxf(h, 0.f);
                p0 += h * oW[2 * colc];
                p1 += h * oW[2 * colc + 1];
            }
        }
#pragma unroll
        for (int m = 8; m >= 1; m >>= 1) {
            p0 += __shfl_xor(p0, m, 16);
            p1 += __shfl_xor(p1, m, 16);
        }
        if (l16 == 0) {
            int gr = rbase + r;
            if (gr < NN) {
                float l0 = p0 + ob[0], l1 = p1 + ob[1];
                float mx = fmaxf(l0, l1);
                float e0 = __expf(l0 - mx), e1 = __expf(l1 - mx);
                float inv = 1.f / (e0 + e1);
                float2 pr = {e0 * inv, e1 * inv};
                *(float2*)(P + 2 * gr) = pr;
            }
        }
    }
}

// ---- final gather ----
__global__ void k_gather(const int* __restrict__ sidx, const int* __restrict__ oe,
                         const float* __restrict__ P, float* __restrict__ out) {
    int i = blockIdx.x * 256 + threadIdx.x;
    if (i >= NS) return;
    int node = oe[sidx[i]];
    float2 v = *(const float2*)(P + 2 * node);
    *(float2*)(out + 2 * i) = v;
}

extern "C" void kernel_launch(void* const* d_in, const int* in_sizes, int n_in,
                              void* d_out, int out_size, void* d_ws, size_t ws_size,
                              hipStream_t stream) {
    const float* node_state = (const float*)d_in[0];
    const int* ei   = (const int*)d_in[1];
    const int* oe   = (const int*)d_in[2];
    const int* sidx = (const int*)d_in[3];
    const float* W1 = (const float*)d_in[4];
    const float* b1 = (const float*)d_in[5];
    const float* W2 = (const float*)d_in[6];
    const float* b2 = (const float*)d_in[7];
    const float* dW = (const float*)d_in[8];
    const float* db = (const float*)d_in[9];
    const float* oW = (const float*)d_in[10];
    const float* ob = (const float*)d_in[11];
    float* out = (float*)d_out;

    char* ws = (char*)d_ws;
    size_t off = 0;
    auto carve = [&](size_t bytes) -> char* {
        char* p = ws + off;
        off = (off + bytes + 255) & ~(size_t)255;
        return p;
    };
    float* r       = (float*)carve((size_t)2 * NN * 4);
    int*   row_ptr = (int*)carve((size_t)(NN + 1) * 4);
    int*   col     = (int*)carve((size_t)NE * 4);
    unsigned int* P_hist = (unsigned int*)carve((size_t)2 * NBH * NW * 4);
    unsigned char* baseb = (unsigned char*)carve((size_t)NBH * NN);
    unsigned long long* status = (unsigned long long*)carve(64 * 8);
    unsigned short* t   = (unsigned short*)carve((size_t)NN * DD * 2);
    unsigned short* h   = (unsigned short*)carve((size_t)NN * DD * 2);
    unsigned short* BT1 = (unsigned short*)carve((size_t)DD * DD * 2);
    unsigned short* BT2 = (unsigned short*)carve((size_t)DD * DD * 2);
    unsigned short* BTd = (unsigned short*)carve((size_t)DD * NU * 2);
    float* P = (float*)t;   // alias: t dead after second aggregate

    float* r_out = r;
    float* r_in  = r + NN;

    // CSR build — no global atomics; mid-chain fused into one dispatch
    k_hist<<<dim3(NBH, 2), 256, 0, stream>>>(ei, P_hist, status);
    k_mid<<<256, 256, 0, stream>>>(P_hist, r, W1, W2, dW, BT1, BT2, BTd,
                                   row_ptr, baseb, status);
    k_bucket2<<<NBH, 256, 0, stream>>>(ei, row_ptr, baseb, col);

    // layer 1
    k_gemm_bf<false><<<NB64, 256, 0, stream>>>(node_state, r_out, BT1, t);
    k_aggregate<<<(NN + 15) / 16, 256, 0, stream>>>(t, row_ptr, col, r_in, b1, h);

    // layer 2
    k_gemm_bf<true><<<NB64, 256, 0, stream>>>(h, r_out, BT2, t);
    k_aggregate<<<(NN + 15) / 16, 256, 0, stream>>>(t, row_ptr, col, r_in, b2, h);

    // per-node MLP + softmax, then gather
    k_mlp_mfma<<<NB64, 256, 0, stream>>>(h, BTd, db, oW, ob, P);
    k_gather<<<(NS + 255) / 256, 256, 0, stream>>>(sidx, oe, P, out);
}

// Round 11
// 238.912 us; speedup vs baseline: 1.7421x; 1.0391x over previous
//
#include <hip/hip_runtime.h>

#define NN 50000
#define DD 128
#define NE 600000
#define NP 200000
#define NS 300000
#define NU 256
#define NBH 64
#define EPB 9375    // NE/NBH
#define NW 12500    // NN/4 byte-packed words
#define NB64 782    // ceil(NN/64)
#define NSCAN 49    // ceil(NW/256) blocks own the row_ptr scan

typedef __attribute__((ext_vector_type(8))) short short8;
typedef __attribute__((ext_vector_type(4))) float floatx4;

__device__ inline float bf2f(unsigned int u16) {
    unsigned int x = u16 << 16;
    float f; __builtin_memcpy(&f, &x, 4); return f;
}
__device__ inline unsigned short f2bf(float f) {
    unsigned int x; __builtin_memcpy(&x, &f, 4);
    unsigned int lsb = (x >> 16) & 1u;
    x += 0x7fffu + lsb;
    return (unsigned short)(x >> 16);
}

// ---- per-block byte histograms: grid (NBH, 2); y=0 counts src, y=1 counts dst ----
// also zeroes the lookback status array (consumed by k_mid, stream-ordered).
__global__ __launch_bounds__(256) void k_hist(const int* __restrict__ ei,
                                              unsigned int* __restrict__ P,
                                              unsigned long long* __restrict__ status) {
    __shared__ unsigned int hw[NW];
    int b = blockIdx.x, half = blockIdx.y, tid = threadIdx.x;
    if (b == 0 && half == 0 && tid < 64) status[tid] = 0ull;
    for (int w = tid; w < NW; w += 256) hw[w] = 0;
    __syncthreads();
    const int* src = ei + (size_t)half * NE;
    int e0 = b * EPB, e1 = min(e0 + EPB, NE);
    for (int e = e0 + tid; e < e1; e += 256) {
        int s = src[e];
        atomicAdd(&hw[s >> 2], 1u << ((s & 3) * 8));
    }
    __syncthreads();
    unsigned int* Pb = P + ((size_t)half * NBH + b) * NW;
    for (int w = tid; w < NW; w += 256) Pb[w] = hw[w];
}

// ---- fused mid-chain: reduce+rsqrt, weight cast, row_ptr scan (decoupled
// lookback over 49 block partials), colscan byte-bases. One dispatch. ----
__global__ __launch_bounds__(256) void k_mid(
    const unsigned int* __restrict__ P_hist, float* __restrict__ r,
    const float* __restrict__ W1, const float* __restrict__ W2, const float* __restrict__ dW,
    unsigned short* __restrict__ BT1, unsigned short* __restrict__ BT2,
    unsigned short* __restrict__ BTd,
    int* __restrict__ row_ptr, unsigned char* __restrict__ baseb,
    unsigned long long* __restrict__ status)
{
    int b = blockIdx.x, tid = threadIdx.x, lane = tid & 63, w = tid >> 6;
    int gid = b * 256 + tid;

    // ---- phase A: reduce histogram columns -> counts + rsqrt ----
    int4 v = {0, 0, 0, 0};
    if (gid < NW) {                          // dst half: keep counts for scan, write r_in
        const unsigned int* Ph = P_hist + (size_t)NBH * NW + gid;
        int c0 = 0, c1 = 0, c2 = 0, c3 = 0;
        for (int b2 = 0; b2 < NBH; ++b2) {
            unsigned int x = Ph[(size_t)b2 * NW];
            c0 += x & 0xff; c1 += (x >> 8) & 0xff; c2 += (x >> 16) & 0xff; c3 += x >> 24;
        }
        v = (int4){c0, c1, c2, c3};
        float4 rr = {rsqrtf((float)max(c0, 1)), rsqrtf((float)max(c1, 1)),
                     rsqrtf((float)max(c2, 1)), rsqrtf((float)max(c3, 1))};
        *(float4*)(r + NN + gid * 4) = rr;
    } else if (gid < 2 * NW) {               // src half: write r_out
        int wl = gid - NW;
        const unsigned int* Ph = P_hist + wl;
        int c0 = 0, c1 = 0, c2 = 0, c3 = 0;
        for (int b2 = 0; b2 < NBH; ++b2) {
            unsigned int x = Ph[(size_t)b2 * NW];
            c0 += x & 0xff; c1 += (x >> 8) & 0xff; c2 += (x >> 16) & 0xff; c3 += x >> 24;
        }
        float4 rr = {rsqrtf((float)max(c0, 1)), rsqrtf((float)max(c1, 1)),
                     rsqrtf((float)max(c2, 1)), rsqrtf((float)max(c3, 1))};
        *(float4*)(r + wl * 4) = rr;
    }

    // ---- phase B: weight transpose + bf16 cast ----
    {
        int t = gid;
        if (t < 16384) { int rr = t >> 7, cc = t & 127; BT1[cc * 128 + rr] = f2bf(W1[t]); }
        else if (t < 32768) { int t2 = t - 16384; int rr = t2 >> 7, cc = t2 & 127; BT2[cc * 128 + rr] = f2bf(W2[t2]); }
        else if (t < 65536) { int t2 = t - 32768; int rr = t2 >> 8, cc = t2 & 255; BTd[cc * 128 + rr] = f2bf(dW[t2]); }
    }

    // ---- phase C: scan blocks (0..48) build row_ptr via decoupled lookback ----
    if (b < NSCAN) {
        __shared__ int wsum[4];
        __shared__ long long sbase;
        int tot = v.x + v.y + v.z + v.w;
        int x = tot;
#pragma unroll
        for (int off = 1; off < 64; off <<= 1) {
            int y = __shfl_up(x, off);
            if (lane >= off) x += y;
        }
        if (lane == 63) wsum[w] = x;
        __syncthreads();
        int woff = 0;
#pragma unroll
        for (int i = 0; i < 4; ++i) if (i < w) woff += wsum[i];
        if (tid == 0) {
            int btot = wsum[0] + wsum[1] + wsum[2] + wsum[3];
            if (b == 0) {
                sbase = 0;
                __threadfence();
                atomicExch(&status[0], (2ull << 62) | (unsigned long long)btot);
            } else {
                __threadfence();
                atomicExch(&status[b], (1ull << 62) | (unsigned long long)btot);
                long long run = 0; int j = b - 1;
                while (true) {
                    unsigned long long s;
                    do { s = atomicAdd(&status[j], 0ull); } while (s == 0ull);
                    run += (long long)(s & 0x3fffffffffffffffull);
                    if ((s >> 62) == 2ull) break;
                    --j;
                }
                sbase = run;
                __threadfence();
                atomicExch(&status[b], (2ull << 62) | (unsigned long long)(run + btot));
            }
        }
        __syncthreads();
        if (gid < NW) {
            int base = (int)sbase + woff + (x - tot);
            int4 o = {base, base + v.x, base + v.x + v.y, base + v.x + v.y + v.z};
            *(int4*)(row_ptr + gid * 4) = o;
        }
        if (b == 0 && tid == 0) row_ptr[NN] = NE;
    }

    // ---- phase D: colscan byte-bases (blocks NSCAN..NSCAN+195) ----
    int cb = b - NSCAN;
    if (cb >= 0 && cb < 196) {
        int n = cb * 256 + tid;
        if (n < NN) {
            int wl = n >> 2, sh = (n & 3) * 8;
            int run = 0;
            const unsigned int* Pd = P_hist + (size_t)NBH * NW;
            for (int b2 = 0; b2 < NBH; ++b2) {
                baseb[(size_t)b2 * NN + n] = (unsigned char)run;
                run += (Pd[(size_t)b2 * NW + wl] >> sh) & 0xff;
            }
        }
    }
}

// ---- wide kernel: blocks 0..NBH-1 bucket edges; blocks NBH.. do layer-1 GEMM ----
// Both depend only on k_mid; merging lets the short GEMM hide under the bucket.
__global__ __launch_bounds__(256) void k_gemm1_bucket(
    const float* __restrict__ A, const float* __restrict__ rs,
    const unsigned short* __restrict__ BT, unsigned short* __restrict__ Cm,
    const int* __restrict__ ei, const int* __restrict__ row_ptr,
    const unsigned char* __restrict__ baseb, int* __restrict__ col)
{
    __shared__ unsigned short sm[26112];   // 52224 B: GEMM tiles / bucket cursors (union)
    int b = blockIdx.x, tid = threadIdx.x;

    if (b < NBH) {
        // ---- bucket role ----
        unsigned int* cw = (unsigned int*)sm;
        for (int w = tid; w < NW; w += 256) cw[w] = 0;
        __syncthreads();
        const unsigned char* bt = baseb + (size_t)b * NN;
        int e0 = b * EPB, e1 = min(e0 + EPB, NE);
        for (int e = e0 + tid; e < e1; e += 256) {
            int s = ei[e], d = ei[NE + e];
            int sh = (d & 3) * 8;
            unsigned int old = atomicAdd(&cw[d >> 2], 1u << sh);
            col[row_ptr[d] + (int)bt[d] + ((old >> sh) & 0xff)] = s;
        }
        return;
    }

    // ---- GEMM role: t = (bf16(A_f32) @ W1) * r_out ----
    unsigned short (*As)[136] = (unsigned short(*)[136])sm;
    unsigned short (*Bs)[136] = (unsigned short(*)[136])(sm + 64 * 136);
    int lane = tid & 63, wave = tid >> 6;
    int quad = lane >> 4, l16 = lane & 15;
    int row0 = (b - NBH) * 64;

#pragma unroll
    for (int p = 0; p < 8; ++p) {
        int fid = tid + p * 256;
        int r = fid >> 5, c = fid & 31;
        int gr = row0 + r; if (gr > NN - 1) gr = NN - 1;
        float4 v = *(const float4*)(A + (size_t)gr * DD + c * 4);
        ushort4 u;
        u.x = f2bf(v.x); u.y = f2bf(v.y); u.z = f2bf(v.z); u.w = f2bf(v.w);
        *(ushort4*)&As[r][c * 4] = u;
    }
#pragma unroll
    for (int p = 0; p < 8; ++p) {
        int fid = tid + p * 256;
        int r = fid >> 4, c = fid & 15;
        *(uint4*)&Bs[r][c * 8] = *(const uint4*)(BT + (size_t)r * DD + c * 8);
    }
    __syncthreads();

    short8 af[4];
#pragma unroll
    for (int ks = 0; ks < 4; ++ks)
        af[ks] = *(const short8*)&As[wave * 16 + l16][ks * 32 + quad * 8];
    floatx4 acc[8];
#pragma unroll
    for (int nt = 0; nt < 8; ++nt) acc[nt] = (floatx4){0.f, 0.f, 0.f, 0.f};
#pragma unroll
    for (int ks = 0; ks < 4; ++ks) {
#pragma unroll
        for (int nt = 0; nt < 8; ++nt) {
            short8 bf = *(const short8*)&Bs[nt * 16 + l16][ks * 32 + quad * 8];
            acc[nt] = __builtin_amdgcn_mfma_f32_16x16x32_bf16(af[ks], bf, acc[nt], 0, 0, 0);
        }
    }
    int rbase = row0 + wave * 16 + quad * 4;
#pragma unroll
    for (int r = 0; r < 4; ++r) {
        int gr = rbase + r;
        if (gr < NN) {
            float s = rs[gr];
#pragma unroll
            for (int nt = 0; nt < 8; ++nt)
                Cm[(size_t)gr * DD + nt * 16 + l16] = f2bf(acc[nt][r] * s);
        }
    }
}

// ---- MFMA GEMM (layer 2): Cm = rowscale(A_bf16 @ W2) ----
__global__ __launch_bounds__(256) void k_gemm_bf(const unsigned short* __restrict__ A,
                                                 const float* __restrict__ rs,
                                                 const unsigned short* __restrict__ BT,
                                                 unsigned short* __restrict__ Cm) {
    __shared__ unsigned short As[64][136];
    __shared__ unsigned short Bs[128][136];
    int tid = threadIdx.x, lane = tid & 63, wave = tid >> 6;
    int quad = lane >> 4, l16 = lane & 15;
    int row0 = blockIdx.x * 64;

#pragma unroll
    for (int p = 0; p < 4; ++p) {
        int fid = tid + p * 256;
        int r = fid >> 4, c = fid & 15;
        int gr = row0 + r; if (gr > NN - 1) gr = NN - 1;
        *(uint4*)&As[r][c * 8] = *(const uint4*)(A + (size_t)gr * DD + c * 8);
    }
#pragma unroll
    for (int p = 0; p < 8; ++p) {
        int fid = tid + p * 256;
        int r = fid >> 4, c = fid & 15;
        *(uint4*)&Bs[r][c * 8] = *(const uint4*)(BT + (size_t)r * DD + c * 8);
    }
    __syncthreads();

    short8 af[4];
#pragma unroll
    for (int ks = 0; ks < 4; ++ks)
        af[ks] = *(const short8*)&As[wave * 16 + l16][ks * 32 + quad * 8];
    floatx4 acc[8];
#pragma unroll
    for (int nt = 0; nt < 8; ++nt) acc[nt] = (floatx4){0.f, 0.f, 0.f, 0.f};
#pragma unroll
    for (int ks = 0; ks < 4; ++ks) {
#pragma unroll
        for (int nt = 0; nt < 8; ++nt) {
            short8 bf = *(const short8*)&Bs[nt * 16 + l16][ks * 32 + quad * 8];
            acc[nt] = __builtin_amdgcn_mfma_f32_16x16x32_bf16(af[ks], bf, acc[nt], 0, 0, 0);
        }
    }
    int rbase = row0 + wave * 16 + quad * 4;
#pragma unroll
    for (int r = 0; r < 4; ++r) {
        int gr = rbase + r;
        if (gr < NN) {
            float s = rs[gr];
#pragma unroll
            for (int nt = 0; nt < 8; ++nt)
                Cm[(size_t)gr * DD + nt * 16 + l16] = f2bf(acc[nt][r] * s);
        }
    }
}

// ---- CSR aggregate + fused finalize: H[n] = bf16((sum T[s]) * r_in[n] + b) ----
// 16 lanes/node, uint4/lane; 4 gathers in flight for memory-level parallelism.
__global__ __launch_bounds__(256) void k_aggregate(const unsigned short* __restrict__ T,
                                                   const int* __restrict__ row_ptr,
                                                   const int* __restrict__ col,
                                                   const float* __restrict__ r_in,
                                                   const float* __restrict__ b,
                                                   unsigned short* __restrict__ H) {
    int wave = threadIdx.x >> 6, lane = threadIdx.x & 63;
    int sub = lane >> 4, l16 = lane & 15;
    int node = blockIdx.x * 16 + wave * 4 + sub;
    if (node >= NN) return;
    int beg = row_ptr[node], end = row_ptr[node + 1];
    float a0 = 0.f, a1 = 0.f, a2 = 0.f, a3 = 0.f, a4 = 0.f, a5 = 0.f, a6 = 0.f, a7 = 0.f;
    for (int base = beg; base < end; base += 16) {
        int m = end - base; if (m > 16) m = 16;
        int myidx = (l16 < m) ? col[base + l16] : 0;
        int j = 0;
        for (; j + 4 <= m; j += 4) {
            int s0 = __shfl(myidx, (sub << 4) | j);
            int s1 = __shfl(myidx, (sub << 4) | (j + 1));
            int s2 = __shfl(myidx, (sub << 4) | (j + 2));
            int s3 = __shfl(myidx, (sub << 4) | (j + 3));
            uint4 v0 = *(const uint4*)(T + (size_t)s0 * DD + l16 * 8);
            uint4 v1 = *(const uint4*)(T + (size_t)s1 * DD + l16 * 8);
            uint4 v2 = *(const uint4*)(T + (size_t)s2 * DD + l16 * 8);
            uint4 v3 = *(const uint4*)(T + (size_t)s3 * DD + l16 * 8);
            a0 += bf2f(v0.x & 0xffff) + bf2f(v1.x & 0xffff) + bf2f(v2.x & 0xffff) + bf2f(v3.x & 0xffff);
            a1 += bf2f(v0.x >> 16)    + bf2f(v1.x >> 16)    + bf2f(v2.x >> 16)    + bf2f(v3.x >> 16);
            a2 += bf2f(v0.y & 0xffff) + bf2f(v1.y & 0xffff) + bf2f(v2.y & 0xffff) + bf2f(v3.y & 0xffff);
            a3 += bf2f(v0.y >> 16)    + bf2f(v1.y >> 16)    + bf2f(v2.y >> 16)    + bf2f(v3.y >> 16);
            a4 += bf2f(v0.z & 0xffff) + bf2f(v1.z & 0xffff) + bf2f(v2.z & 0xffff) + bf2f(v3.z & 0xffff);
            a5 += bf2f(v0.z >> 16)    + bf2f(v1.z >> 16)    + bf2f(v2.z >> 16)    + bf2f(v3.z >> 16);
            a6 += bf2f(v0.w & 0xffff) + bf2f(v1.w & 0xffff) + bf2f(v2.w & 0xffff) + bf2f(v3.w & 0xffff);
            a7 += bf2f(v0.w >> 16)    + bf2f(v1.w >> 16)    + bf2f(v2.w >> 16)    + bf2f(v3.w >> 16);
        }
        for (; j < m; ++j) {
            int s0 = __shfl(myidx, (sub << 4) | j);
            uint4 v0 = *(const uint4*)(T + (size_t)s0 * DD + l16 * 8);
            a0 += bf2f(v0.x & 0xffff); a1 += bf2f(v0.x >> 16);
            a2 += bf2f(v0.y & 0xffff); a3 += bf2f(v0.y >> 16);
            a4 += bf2f(v0.z & 0xffff); a5 += bf2f(v0.z >> 16);
            a6 += bf2f(v0.w & 0xffff); a7 += bf2f(v0.w >> 16);
        }
    }
    float rv = r_in[node];
    float4 bl = *(const float4*)(b + l16 * 8);
    float4 bh = *(const float4*)(b + l16 * 8 + 4);
    uint4 w;
    w.x = (unsigned int)f2bf(a0 * rv + bl.x) | ((unsigned int)f2bf(a1 * rv + bl.y) << 16);
    w.y = (unsigned int)f2bf(a2 * rv + bl.z) | ((unsigned int)f2bf(a3 * rv + bl.w) << 16);
    w.z = (unsigned int)f2bf(a4 * rv + bh.x) | ((unsigned int)f2bf(a5 * rv + bh.y) << 16);
    w.w = (unsigned int)f2bf(a6 * rv + bh.z) | ((unsigned int)f2bf(a7 * rv + bh.w) << 16);
    *(uint4*)(H + (size_t)node * DD + l16 * 8) = w;
}

// ---- MFMA MLP: P[n] = softmax(relu(h2[n]@dW + db)@oW + ob) ----
__global__ __launch_bounds__(256) void k_mlp_mfma(const unsigned short* __restrict__ H2,
                                                  const unsigned short* __restrict__ BTd,
                                                  const float* __restrict__ db,
                                                  const float* __restrict__ oW,
                                                  const float* __restrict__ ob,
                                                  float* __restrict__ P) {
    __shared__ unsigned short As[64][136];
    __shared__ unsigned short Bs[128][136];
    int tid = threadIdx.x, lane = tid & 63, wave = tid >> 6;
    int quad = lane >> 4, l16 = lane & 15;
    int row0 = blockIdx.x * 64;
#pragma unroll
    for (int p = 0; p < 4; ++p) {
        int fid = tid + p * 256;
        int r = fid >> 4, c = fid & 15;
        int gr = row0 + r; if (gr > NN - 1) gr = NN - 1;
        *(uint4*)&As[r][c * 8] = *(const uint4*)(H2 + (size_t)gr * DD + c * 8);
    }
    short8 af[4];
    floatx4 acc[16];
#pragma unroll
    for (int i = 0; i < 16; ++i) acc[i] = (floatx4){0.f, 0.f, 0.f, 0.f};

    for (int ch = 0; ch < 2; ++ch) {
        __syncthreads();
#pragma unroll
        for (int p = 0; p < 8; ++p) {
            int fid = tid + p * 256;
            int r = fid >> 4, c = fid & 15;
            *(uint4*)&Bs[r][c * 8] = *(const uint4*)(BTd + (size_t)(ch * 128 + r) * DD + c * 8);
        }
        __syncthreads();
        if (ch == 0) {
#pragma unroll
            for (int ks = 0; ks < 4; ++ks)
                af[ks] = *(const short8*)&As[wave * 16 + l16][ks * 32 + quad * 8];
        }
#pragma unroll
        for (int ks = 0; ks < 4; ++ks) {
#pragma unroll
            for (int nt = 0; nt < 8; ++nt) {
                short8 bf = *(const short8*)&Bs[nt * 16 + l16][ks * 32 + quad * 8];
                acc[ch * 8 + nt] =
                    __builtin_amdgcn_mfma_f32_16x16x32_bf16(af[ks], bf, acc[ch * 8 + nt], 0, 0, 0);
            }
        }
    }
    int rbase = row0 + wave * 16 + quad * 4;
#pragma unroll
    for (int r = 0; r < 4; ++r) {
        float p0 = 0.f, p1 = 0.f;
#pragma unroll
        for (int ch = 0; ch < 2; ++ch) {
#pragma unroll
            for (int nt = 0; nt < 8; ++nt) {
                int colc = ch * 128 + nt * 16 + l16;
                float h = acc[ch * 8 + nt][r] + db[colc];
                h = fmaxf(h, 0.f);
                p0 += h * oW[2 * colc];
                p1 += h * oW[2 * colc + 1];
            }
        }
#pragma unroll
        for (int m = 8; m >= 1; m >>= 1) {
            p0 += __shfl_xor(p0, m, 16);
            p1 += __shfl_xor(p1, m, 16);
        }
        if (l16 == 0) {
            int gr = rbase + r;
            if (gr < NN) {
                float l0 = p0 + ob[0], l1 = p1 + ob[1];
                float mx = fmaxf(l0, l1);
                float e0 = __expf(l0 - mx), e1 = __expf(l1 - mx);
                float inv = 1.f / (e0 + e1);
                float2 pr = {e0 * inv, e1 * inv};
                *(float2*)(P + 2 * gr) = pr;
            }
        }
    }
}

// ---- final gather ----
__global__ void k_gather(const int* __restrict__ sidx, const int* __restrict__ oe,
                         const float* __restrict__ P, float* __restrict__ out) {
    int i = blockIdx.x * 256 + threadIdx.x;
    if (i >= NS) return;
    int node = oe[sidx[i]];
    float2 v = *(const float2*)(P + 2 * node);
    *(float2*)(out + 2 * i) = v;
}

extern "C" void kernel_launch(void* const* d_in, const int* in_sizes, int n_in,
                              void* d_out, int out_size, void* d_ws, size_t ws_size,
                              hipStream_t stream) {
    const float* node_state = (const float*)d_in[0];
    const int* ei   = (const int*)d_in[1];
    const int* oe   = (const int*)d_in[2];
    const int* sidx = (const int*)d_in[3];
    const float* W1 = (const float*)d_in[4];
    const float* b1 = (const float*)d_in[5];
    const float* W2 = (const float*)d_in[6];
    const float* b2 = (const float*)d_in[7];
    const float* dW = (const float*)d_in[8];
    const float* db = (const float*)d_in[9];
    const float* oW = (const float*)d_in[10];
    const float* ob = (const float*)d_in[11];
    float* out = (float*)d_out;

    char* ws = (char*)d_ws;
    size_t off = 0;
    auto carve = [&](size_t bytes) -> char* {
        char* p = ws + off;
        off = (off + bytes + 255) & ~(size_t)255;
        return p;
    };
    float* r       = (float*)carve((size_t)2 * NN * 4);
    int*   row_ptr = (int*)carve((size_t)(NN + 1) * 4);
    int*   col     = (int*)carve((size_t)NE * 4);
    unsigned int* P_hist = (unsigned int*)carve((size_t)2 * NBH * NW * 4);
    unsigned char* baseb = (unsigned char*)carve((size_t)NBH * NN);
    unsigned long long* status = (unsigned long long*)carve(64 * 8);
    unsigned short* t   = (unsigned short*)carve((size_t)NN * DD * 2);
    unsigned short* h   = (unsigned short*)carve((size_t)NN * DD * 2);
    unsigned short* BT1 = (unsigned short*)carve((size_t)DD * DD * 2);
    unsigned short* BT2 = (unsigned short*)carve((size_t)DD * DD * 2);
    unsigned short* BTd = (unsigned short*)carve((size_t)DD * NU * 2);
    float* P = (float*)t;   // alias: t dead after second aggregate

    float* r_out = r;
    float* r_in  = r + NN;

    // CSR build — no global atomics; mid-chain fused into one dispatch
    k_hist<<<dim3(NBH, 2), 256, 0, stream>>>(ei, P_hist, status);
    k_mid<<<256, 256, 0, stream>>>(P_hist, r, W1, W2, dW, BT1, BT2, BTd,
                                   row_ptr, baseb, status);

    // bucket + layer-1 GEMM in one wide kernel (independent given k_mid)
    k_gemm1_bucket<<<NBH + NB64, 256, 0, stream>>>(node_state, r_out, BT1, t,
                                                   ei, row_ptr, baseb, col);
    k_aggregate<<<(NN + 15) / 16, 256, 0, stream>>>(t, row_ptr, col, r_in, b1, h);

    // layer 2
    k_gemm_bf<<<NB64, 256, 0, stream>>>(h, r_out, BT2, t);
    k_aggregate<<<(NN + 15) / 16, 256, 0, stream>>>(t, row_ptr, col, r_in, b2, h);

    // per-node MLP + softmax, then gather
    k_mlp_mfma<<<NB64, 256, 0, stream>>>(h, BTd, db, oW, ob, P);
    k_gather<<<(NS + 255) / 256, 256, 0, stream>>>(sidx, oe, P, out);
}

// Round 12
// 231.822 us; speedup vs baseline: 1.7954x; 1.0306x over previous
//
#include <hip/hip_runtime.h>

#define NN 50000
#define DD 128
#define NE 600000
#define NP 200000
#define NS 300000
#define NU 256
#define NBH 128
#define EPB 4688    // ceil(NE/NBH)
#define NW 12500    // NN/4 byte-packed words
#define NB64 782    // ceil(NN/64)
#define NSCAN 49    // ceil(NW/256) blocks own the row_ptr scan

typedef __attribute__((ext_vector_type(8))) short short8;
typedef __attribute__((ext_vector_type(4))) float floatx4;

__device__ inline float bf2f(unsigned int u16) {
    unsigned int x = u16 << 16;
    float f; __builtin_memcpy(&f, &x, 4); return f;
}
__device__ inline unsigned short f2bf(float f) {
    unsigned int x; __builtin_memcpy(&x, &f, 4);
    unsigned int lsb = (x >> 16) & 1u;
    x += 0x7fffu + lsb;
    return (unsigned short)(x >> 16);
}

// ---- per-block byte histograms: grid (NBH, 2); y=0 counts src, y=1 counts dst ----
// also zeroes the lookback status array (consumed by k_mid, stream-ordered).
__global__ __launch_bounds__(256) void k_hist(const int* __restrict__ ei,
                                              unsigned int* __restrict__ P,
                                              unsigned long long* __restrict__ status) {
    __shared__ unsigned int hw[NW];
    int b = blockIdx.x, half = blockIdx.y, tid = threadIdx.x;
    if (b == 0 && half == 0 && tid < 64) status[tid] = 0ull;
    for (int w = tid; w < NW; w += 256) hw[w] = 0;
    __syncthreads();
    const int* src = ei + (size_t)half * NE;
    int e0 = b * EPB, e1 = min(e0 + EPB, NE);
    for (int e = e0 + tid; e < e1; e += 256) {
        int s = src[e];
        atomicAdd(&hw[s >> 2], 1u << ((s & 3) * 8));
    }
    __syncthreads();
    unsigned int* Pb = P + ((size_t)half * NBH + b) * NW;
    for (int w = tid; w < NW; w += 256) Pb[w] = hw[w];
}

// ---- fused mid-chain: reduce+rsqrt, weight cast, row_ptr scan (decoupled
// lookback over 49 block partials), colscan byte-bases. One dispatch. ----
__global__ __launch_bounds__(256) void k_mid(
    const unsigned int* __restrict__ P_hist, float* __restrict__ r,
    const float* __restrict__ W1, const float* __restrict__ W2, const float* __restrict__ dW,
    unsigned short* __restrict__ BT1, unsigned short* __restrict__ BT2,
    unsigned short* __restrict__ BTd,
    int* __restrict__ row_ptr, unsigned char* __restrict__ baseb,
    unsigned long long* __restrict__ status)
{
    int b = blockIdx.x, tid = threadIdx.x, lane = tid & 63, w = tid >> 6;
    int gid = b * 256 + tid;

    // ---- phase A: reduce histogram columns -> counts + rsqrt ----
    int4 v = {0, 0, 0, 0};
    if (gid < NW) {                          // dst half: keep counts for scan, write r_in
        const unsigned int* Ph = P_hist + (size_t)NBH * NW + gid;
        int c0 = 0, c1 = 0, c2 = 0, c3 = 0;
        for (int b2 = 0; b2 < NBH; ++b2) {
            unsigned int x = Ph[(size_t)b2 * NW];
            c0 += x & 0xff; c1 += (x >> 8) & 0xff; c2 += (x >> 16) & 0xff; c3 += x >> 24;
        }
        v = (int4){c0, c1, c2, c3};
        float4 rr = {rsqrtf((float)max(c0, 1)), rsqrtf((float)max(c1, 1)),
                     rsqrtf((float)max(c2, 1)), rsqrtf((float)max(c3, 1))};
        *(float4*)(r + NN + gid * 4) = rr;
    } else if (gid < 2 * NW) {               // src half: write r_out
        int wl = gid - NW;
        const unsigned int* Ph = P_hist + wl;
        int c0 = 0, c1 = 0, c2 = 0, c3 = 0;
        for (int b2 = 0; b2 < NBH; ++b2) {
            unsigned int x = Ph[(size_t)b2 * NW];
            c0 += x & 0xff; c1 += (x >> 8) & 0xff; c2 += (x >> 16) & 0xff; c3 += x >> 24;
        }
        float4 rr = {rsqrtf((float)max(c0, 1)), rsqrtf((float)max(c1, 1)),
                     rsqrtf((float)max(c2, 1)), rsqrtf((float)max(c3, 1))};
        *(float4*)(r + wl * 4) = rr;
    }

    // ---- phase B: weight transpose + bf16 cast ----
    {
        int t = gid;
        if (t < 16384) { int rr = t >> 7, cc = t & 127; BT1[cc * 128 + rr] = f2bf(W1[t]); }
        else if (t < 32768) { int t2 = t - 16384; int rr = t2 >> 7, cc = t2 & 127; BT2[cc * 128 + rr] = f2bf(W2[t2]); }
        else if (t < 65536) { int t2 = t - 32768; int rr = t2 >> 8, cc = t2 & 255; BTd[cc * 128 + rr] = f2bf(dW[t2]); }
    }

    // ---- phase C: scan blocks (0..48) build row_ptr via decoupled lookback ----
    if (b < NSCAN) {
        __shared__ int wsum[4];
        __shared__ long long sbase;
        int tot = v.x + v.y + v.z + v.w;
        int x = tot;
#pragma unroll
        for (int off = 1; off < 64; off <<= 1) {
            int y = __shfl_up(x, off);
            if (lane >= off) x += y;
        }
        if (lane == 63) wsum[w] = x;
        __syncthreads();
        int woff = 0;
#pragma unroll
        for (int i = 0; i < 4; ++i) if (i < w) woff += wsum[i];
        if (tid == 0) {
            int btot = wsum[0] + wsum[1] + wsum[2] + wsum[3];
            if (b == 0) {
                sbase = 0;
                __threadfence();
                atomicExch(&status[0], (2ull << 62) | (unsigned long long)btot);
            } else {
                __threadfence();
                atomicExch(&status[b], (1ull << 62) | (unsigned long long)btot);
                long long run = 0; int j = b - 1;
                while (true) {
                    unsigned long long s;
                    do { s = atomicAdd(&status[j], 0ull); } while (s == 0ull);
                    run += (long long)(s & 0x3fffffffffffffffull);
                    if ((s >> 62) == 2ull) break;
                    --j;
                }
                sbase = run;
                __threadfence();
                atomicExch(&status[b], (2ull << 62) | (unsigned long long)(run + btot));
            }
        }
        __syncthreads();
        if (gid < NW) {
            int base = (int)sbase + woff + (x - tot);
            int4 o = {base, base + v.x, base + v.x + v.y, base + v.x + v.y + v.z};
            *(int4*)(row_ptr + gid * 4) = o;
        }
        if (b == 0 && tid == 0) row_ptr[NN] = NE;
    }

    // ---- phase D: colscan byte-bases (blocks NSCAN..NSCAN+195) ----
    int cb = b - NSCAN;
    if (cb >= 0 && cb < 196) {
        int n = cb * 256 + tid;
        if (n < NN) {
            int wl = n >> 2, sh = (n & 3) * 8;
            int run = 0;
            const unsigned int* Pd = P_hist + (size_t)NBH * NW;
            for (int b2 = 0; b2 < NBH; ++b2) {
                baseb[(size_t)b2 * NN + n] = (unsigned char)run;
                run += (Pd[(size_t)b2 * NW + wl] >> sh) & 0xff;
            }
        }
    }
}

// ---- wide kernel: blocks 0..NBH-1 bucket edges; blocks NBH.. do layer-1 GEMM ----
// Both depend only on k_mid; merging lets the short GEMM hide under the bucket.
__global__ __launch_bounds__(256) void k_gemm1_bucket(
    const float* __restrict__ A, const float* __restrict__ rs,
    const unsigned short* __restrict__ BT, unsigned short* __restrict__ Cm,
    const int* __restrict__ ei, const int* __restrict__ row_ptr,
    const unsigned char* __restrict__ baseb, int* __restrict__ col)
{
    __shared__ unsigned short sm[26112];   // 52224 B: GEMM tiles / bucket cursors (union)
    int b = blockIdx.x, tid = threadIdx.x;

    if (b < NBH) {
        // ---- bucket role ----
        unsigned int* cw = (unsigned int*)sm;
        for (int w = tid; w < NW; w += 256) cw[w] = 0;
        __syncthreads();
        const unsigned char* bt = baseb + (size_t)b * NN;
        int e0 = b * EPB, e1 = min(e0 + EPB, NE);
        for (int e = e0 + tid; e < e1; e += 256) {
            int s = ei[e], d = ei[NE + e];
            int sh = (d & 3) * 8;
            unsigned int old = atomicAdd(&cw[d >> 2], 1u << sh);
            col[row_ptr[d] + (int)bt[d] + ((old >> sh) & 0xff)] = s;
        }
        return;
    }

    // ---- GEMM role: t = (bf16(A_f32) @ W1) * r_out ----
    unsigned short (*As)[136] = (unsigned short(*)[136])sm;
    unsigned short (*Bs)[136] = (unsigned short(*)[136])(sm + 64 * 136);
    int lane = tid & 63, wave = tid >> 6;
    int quad = lane >> 4, l16 = lane & 15;
    int row0 = (b - NBH) * 64;

#pragma unroll
    for (int p = 0; p < 8; ++p) {
        int fid = tid + p * 256;
        int r = fid >> 5, c = fid & 31;
        int gr = row0 + r; if (gr > NN - 1) gr = NN - 1;
        float4 v = *(const float4*)(A + (size_t)gr * DD + c * 4);
        ushort4 u;
        u.x = f2bf(v.x); u.y = f2bf(v.y); u.z = f2bf(v.z); u.w = f2bf(v.w);
        *(ushort4*)&As[r][c * 4] = u;
    }
#pragma unroll
    for (int p = 0; p < 8; ++p) {
        int fid = tid + p * 256;
        int r = fid >> 4, c = fid & 15;
        *(uint4*)&Bs[r][c * 8] = *(const uint4*)(BT + (size_t)r * DD + c * 8);
    }
    __syncthreads();

    short8 af[4];
#pragma unroll
    for (int ks = 0; ks < 4; ++ks)
        af[ks] = *(const short8*)&As[wave * 16 + l16][ks * 32 + quad * 8];
    floatx4 acc[8];
#pragma unroll
    for (int nt = 0; nt < 8; ++nt) acc[nt] = (floatx4){0.f, 0.f, 0.f, 0.f};
#pragma unroll
    for (int ks = 0; ks < 4; ++ks) {
#pragma unroll
        for (int nt = 0; nt < 8; ++nt) {
            short8 bf = *(const short8*)&Bs[nt * 16 + l16][ks * 32 + quad * 8];
            acc[nt] = __builtin_amdgcn_mfma_f32_16x16x32_bf16(af[ks], bf, acc[nt], 0, 0, 0);
        }
    }
    int rbase = row0 + wave * 16 + quad * 4;
#pragma unroll
    for (int r = 0; r < 4; ++r) {
        int gr = rbase + r;
        if (gr < NN) {
            float s = rs[gr];
#pragma unroll
            for (int nt = 0; nt < 8; ++nt)
                Cm[(size_t)gr * DD + nt * 16 + l16] = f2bf(acc[nt][r] * s);
        }
    }
}

// ---- MFMA GEMM (layer 2): Cm = rowscale(A_bf16 @ W2) ----
__global__ __launch_bounds__(256) void k_gemm_bf(const unsigned short* __restrict__ A,
                                                 const float* __restrict__ rs,
                                                 const unsigned short* __restrict__ BT,
                                                 unsigned short* __restrict__ Cm) {
    __shared__ unsigned short As[64][136];
    __shared__ unsigned short Bs[128][136];
    int tid = threadIdx.x, lane = tid & 63, wave = tid >> 6;
    int quad = lane >> 4, l16 = lane & 15;
    int row0 = blockIdx.x * 64;

#pragma unroll
    for (int p = 0; p < 4; ++p) {
        int fid = tid + p * 256;
        int r = fid >> 4, c = fid & 15;
        int gr = row0 + r; if (gr > NN - 1) gr = NN - 1;
        *(uint4*)&As[r][c * 8] = *(const uint4*)(A + (size_t)gr * DD + c * 8);
    }
#pragma unroll
    for (int p = 0; p < 8; ++p) {
        int fid = tid + p * 256;
        int r = fid >> 4, c = fid & 15;
        *(uint4*)&Bs[r][c * 8] = *(const uint4*)(BT + (size_t)r * DD + c * 8);
    }
    __syncthreads();

    short8 af[4];
#pragma unroll
    for (int ks = 0; ks < 4; ++ks)
        af[ks] = *(const short8*)&As[wave * 16 + l16][ks * 32 + quad * 8];
    floatx4 acc[8];
#pragma unroll
    for (int nt = 0; nt < 8; ++nt) acc[nt] = (floatx4){0.f, 0.f, 0.f, 0.f};
#pragma unroll
    for (int ks = 0; ks < 4; ++ks) {
#pragma unroll
        for (int nt = 0; nt < 8; ++nt) {
            short8 bf = *(const short8*)&Bs[nt * 16 + l16][ks * 32 + quad * 8];
            acc[nt] = __builtin_amdgcn_mfma_f32_16x16x32_bf16(af[ks], bf, acc[nt], 0, 0, 0);
        }
    }
    int rbase = row0 + wave * 16 + quad * 4;
#pragma unroll
    for (int r = 0; r < 4; ++r) {
        int gr = rbase + r;
        if (gr < NN) {
            float s = rs[gr];
#pragma unroll
            for (int nt = 0; nt < 8; ++nt)
                Cm[(size_t)gr * DD + nt * 16 + l16] = f2bf(acc[nt][r] * s);
        }
    }
}

// ---- CSR aggregate + fused finalize: H[n] = bf16((sum T[s]) * r_in[n] + b) ----
// 16 lanes/node, uint4/lane; 4 gathers in flight for memory-level parallelism.
__global__ __launch_bounds__(256) void k_aggregate(const unsigned short* __restrict__ T,
                                                   const int* __restrict__ row_ptr,
                                                   const int* __restrict__ col,
                                                   const float* __restrict__ r_in,
                                                   const float* __restrict__ b,
                                                   unsigned short* __restrict__ H) {
    int wave = threadIdx.x >> 6, lane = threadIdx.x & 63;
    int sub = lane >> 4, l16 = lane & 15;
    int node = blockIdx.x * 16 + wave * 4 + sub;
    if (node >= NN) return;
    int beg = row_ptr[node], end = row_ptr[node + 1];
    float a0 = 0.f, a1 = 0.f, a2 = 0.f, a3 = 0.f, a4 = 0.f, a5 = 0.f, a6 = 0.f, a7 = 0.f;
    for (int base = beg; base < end; base += 16) {
        int m = end - base; if (m > 16) m = 16;
        int myidx = (l16 < m) ? col[base + l16] : 0;
        int j = 0;
        for (; j + 4 <= m; j += 4) {
            int s0 = __shfl(myidx, (sub << 4) | j);
            int s1 = __shfl(myidx, (sub << 4) | (j + 1));
            int s2 = __shfl(myidx, (sub << 4) | (j + 2));
            int s3 = __shfl(myidx, (sub << 4) | (j + 3));
            uint4 v0 = *(const uint4*)(T + (size_t)s0 * DD + l16 * 8);
            uint4 v1 = *(const uint4*)(T + (size_t)s1 * DD + l16 * 8);
            uint4 v2 = *(const uint4*)(T + (size_t)s2 * DD + l16 * 8);
            uint4 v3 = *(const uint4*)(T + (size_t)s3 * DD + l16 * 8);
            a0 += bf2f(v0.x & 0xffff) + bf2f(v1.x & 0xffff) + bf2f(v2.x & 0xffff) + bf2f(v3.x & 0xffff);
            a1 += bf2f(v0.x >> 16)    + bf2f(v1.x >> 16)    + bf2f(v2.x >> 16)    + bf2f(v3.x >> 16);
            a2 += bf2f(v0.y & 0xffff) + bf2f(v1.y & 0xffff) + bf2f(v2.y & 0xffff) + bf2f(v3.y & 0xffff);
            a3 += bf2f(v0.y >> 16)    + bf2f(v1.y >> 16)    + bf2f(v2.y >> 16)    + bf2f(v3.y >> 16);
            a4 += bf2f(v0.z & 0xffff) + bf2f(v1.z & 0xffff) + bf2f(v2.z & 0xffff) + bf2f(v3.z & 0xffff);
            a5 += bf2f(v0.z >> 16)    + bf2f(v1.z >> 16)    + bf2f(v2.z >> 16)    + bf2f(v3.z >> 16);
            a6 += bf2f(v0.w & 0xffff) + bf2f(v1.w & 0xffff) + bf2f(v2.w & 0xffff) + bf2f(v3.w & 0xffff);
            a7 += bf2f(v0.w >> 16)    + bf2f(v1.w >> 16)    + bf2f(v2.w >> 16)    + bf2f(v3.w >> 16);
        }
        for (; j < m; ++j) {
            int s0 = __shfl(myidx, (sub << 4) | j);
            uint4 v0 = *(const uint4*)(T + (size_t)s0 * DD + l16 * 8);
            a0 += bf2f(v0.x & 0xffff); a1 += bf2f(v0.x >> 16);
            a2 += bf2f(v0.y & 0xffff); a3 += bf2f(v0.y >> 16);
            a4 += bf2f(v0.z & 0xffff); a5 += bf2f(v0.z >> 16);
            a6 += bf2f(v0.w & 0xffff); a7 += bf2f(v0.w >> 16);
        }
    }
    float rv = r_in[node];
    float4 bl = *(const float4*)(b + l16 * 8);
    float4 bh = *(const float4*)(b + l16 * 8 + 4);
    uint4 w;
    w.x = (unsigned int)f2bf(a0 * rv + bl.x) | ((unsigned int)f2bf(a1 * rv + bl.y) << 16);
    w.y = (unsigned int)f2bf(a2 * rv + bl.z) | ((unsigned int)f2bf(a3 * rv + bl.w) << 16);
    w.z = (unsigned int)f2bf(a4 * rv + bh.x) | ((unsigned int)f2bf(a5 * rv + bh.y) << 16);
    w.w = (unsigned int)f2bf(a6 * rv + bh.z) | ((unsigned int)f2bf(a7 * rv + bh.w) << 16);
    *(uint4*)(H + (size_t)node * DD + l16 * 8) = w;
}

// ---- MFMA MLP: P[n] = softmax(relu(h2[n]@dW + db)@oW + ob) ----
__global__ __launch_bounds__(256) void k_mlp_mfma(const unsigned short* __restrict__ H2,
                                                  const unsigned short* __restrict__ BTd,
                                                  const float* __restrict__ db,
                                                  const float* __restrict__ oW,
                                                  const float* __restrict__ ob,
                                                  float* __restrict__ P) {
    __shared__ unsigned short As[64][136];
    __shared__ unsigned short Bs[128][136];
    int tid = threadIdx.x, lane = tid & 63, wave = tid >> 6;
    int quad = lane >> 4, l16 = lane & 15;
    int row0 = blockIdx.x * 64;
#pragma unroll
    for (int p = 0; p < 4; ++p) {
        int fid = tid + p * 256;
        int r = fid >> 4, c = fid & 15;
        int gr = row0 + r; if (gr > NN - 1) gr = NN - 1;
        *(uint4*)&As[r][c * 8] = *(const uint4*)(H2 + (size_t)gr * DD + c * 8);
    }
    short8 af[4];
    floatx4 acc[16];
#pragma unroll
    for (int i = 0; i < 16; ++i) acc[i] = (floatx4){0.f, 0.f, 0.f, 0.f};

    for (int ch = 0; ch < 2; ++ch) {
        __syncthreads();
#pragma unroll
        for (int p = 0; p < 8; ++p) {
            int fid = tid + p * 256;
            int r = fid >> 4, c = fid & 15;
            *(uint4*)&Bs[r][c * 8] = *(const uint4*)(BTd + (size_t)(ch * 128 + r) * DD + c * 8);
        }
        __syncthreads();
        if (ch == 0) {
#pragma unroll
            for (int ks = 0; ks < 4; ++ks)
                af[ks] = *(const short8*)&As[wave * 16 + l16][ks * 32 + quad * 8];
        }
#pragma unroll
        for (int ks = 0; ks < 4; ++ks) {
#pragma unroll
            for (int nt = 0; nt < 8; ++nt) {
                short8 bf = *(const short8*)&Bs[nt * 16 + l16][ks * 32 + quad * 8];
                acc[ch * 8 + nt] =
                    __builtin_amdgcn_mfma_f32_16x16x32_bf16(af[ks], bf, acc[ch * 8 + nt], 0, 0, 0);
            }
        }
    }
    int rbase = row0 + wave * 16 + quad * 4;
#pragma unroll
    for (int r = 0; r < 4; ++r) {
        float p0 = 0.f, p1 = 0.f;
#pragma unroll
        for (int ch = 0; ch < 2; ++ch) {
#pragma unroll
            for (int nt = 0; nt < 8; ++nt) {
                int colc = ch * 128 + nt * 16 + l16;
                float h = acc[ch * 8 + nt][r] + db[colc];
                h = fmaxf(h, 0.f);
                p0 += h * oW[2 * colc];
                p1 += h * oW[2 * colc + 1];
            }
        }
#pragma unroll
        for (int m = 8; m >= 1; m >>= 1) {
            p0 += __shfl_xor(p0, m, 16);
            p1 += __shfl_xor(p1, m, 16);
        }
        if (l16 == 0) {
            int gr = rbase + r;
            if (gr < NN) {
                float l0 = p0 + ob[0], l1 = p1 + ob[1];
                float mx = fmaxf(l0, l1);
                float e0 = __expf(l0 - mx), e1 = __expf(l1 - mx);
                float inv = 1.f / (e0 + e1);
                float2 pr = {e0 * inv, e1 * inv};
                *(float2*)(P + 2 * gr) = pr;
            }
        }
    }
}

// ---- final gather ----
__global__ void k_gather(const int* __restrict__ sidx, const int* __restrict__ oe,
                         const float* __restrict__ P, float* __restrict__ out) {
    int i = blockIdx.x * 256 + threadIdx.x;
    if (i >= NS) return;
    int node = oe[sidx[i]];
    float2 v = *(const float2*)(P + 2 * node);
    *(float2*)(out + 2 * i) = v;
}

extern "C" void kernel_launch(void* const* d_in, const int* in_sizes, int n_in,
                              void* d_out, int out_size, void* d_ws, size_t ws_size,
                              hipStream_t stream) {
    const float* node_state = (const float*)d_in[0];
    const int* ei   = (const int*)d_in[1];
    const int* oe   = (const int*)d_in[2];
    const int* sidx = (const int*)d_in[3];
    const float* W1 = (const float*)d_in[4];
    const float* b1 = (const float*)d_in[5];
    const float* W2 = (const float*)d_in[6];
    const float* b2 = (const float*)d_in[7];
    const float* dW = (const float*)d_in[8];
    const float* db = (const float*)d_in[9];
    const float* oW = (const float*)d_in[10];
    const float* ob = (const float*)d_in[11];
    float* out = (float*)d_out;

    char* ws = (char*)d_ws;
    size_t off = 0;
    auto carve = [&](size_t bytes) -> char* {
        char* p = ws + off;
        off = (off + bytes + 255) & ~(size_t)255;
        return p;
    };
    float* r       = (float*)carve((size_t)2 * NN * 4);
    int*   row_ptr = (int*)carve((size_t)(NN + 1) * 4);
    int*   col     = (int*)carve((size_t)NE * 4);
    unsigned int* P_hist = (unsigned int*)carve((size_t)2 * NBH * NW * 4);
    unsigned char* baseb = (unsigned char*)carve((size_t)NBH * NN);
    unsigned long long* status = (unsigned long long*)carve(64 * 8);
    unsigned short* t   = (unsigned short*)carve((size_t)NN * DD * 2);
    unsigned short* h   = (unsigned short*)carve((size_t)NN * DD * 2);
    unsigned short* BT1 = (unsigned short*)carve((size_t)DD * DD * 2);
    unsigned short* BT2 = (unsigned short*)carve((size_t)DD * DD * 2);
    unsigned short* BTd = (unsigned short*)carve((size_t)DD * NU * 2);
    float* P = (float*)t;   // alias: t dead after second aggregate

    float* r_out = r;
    float* r_in  = r + NN;

    // CSR build — no global atomics; mid-chain fused into one dispatch
    k_hist<<<dim3(NBH, 2), 256, 0, stream>>>(ei, P_hist, status);
    k_mid<<<256, 256, 0, stream>>>(P_hist, r, W1, W2, dW, BT1, BT2, BTd,
                                   row_ptr, baseb, status);

    // bucket + layer-1 GEMM in one wide kernel (independent given k_mid)
    k_gemm1_bucket<<<NBH + NB64, 256, 0, stream>>>(node_state, r_out, BT1, t,
                                                   ei, row_ptr, baseb, col);
    k_aggregate<<<(NN + 15) / 16, 256, 0, stream>>>(t, row_ptr, col, r_in, b1, h);

    // layer 2
    k_gemm_bf<<<NB64, 256, 0, stream>>>(h, r_out, BT2, t);
    k_aggregate<<<(NN + 15) / 16, 256, 0, stream>>>(t, row_ptr, col, r_in, b2, h);

    // per-node MLP + softmax, then gather
    k_mlp_mfma<<<NB64, 256, 0, stream>>>(h, BTd, db, oW, ob, P);
    k_gather<<<(NS + 255) / 256, 256, 0, stream>>>(sidx, oe, P, out);
}